// Round 1
// baseline (405.278 us; speedup 1.0000x reference)
//
#include <hip/hip_runtime.h>

#define NA 50000
#define NT 25000
#define EAA 800000
#define EAT 400000
#define ETA 400000
#define NSEG 125000          // NA + NA + NT rows: [aa | ta | at]
#define TOTAL_E 1600000
#define NB 489               // coarse buckets of 256 rows
#define NBLK1 391            // pass-1 blocks
#define CHUNK 4096           // edges per pass-1 block
#define CAP 6144             // REC slab capacity per bucket (max observed bucket ~4800)
#define SRCH_STRIDE 75008    // per-copy src-histogram stride: at[50000] | ta[25000] | pad

// conv1 persistent grid: 2048 blocks = 8 blocks/CU on 256 CUs
#define NAB 1564             // agent blocks: 12500 groups -> 8 (or 7) groups/block
#define NTB 484              // target blocks: 6250 groups -> 13 (or 12) groups/block

// ---- workspace layout (4-byte element offsets) ----
#define O_SRCH    0          // int[8*75008]: 8 XCD-local src-degree histogram copies
#define O_BTOT    600064     // int[512]: per-bucket totals (adjacent to SRCH -> single memset)
#define O_RO      600576     // int[125001]: CSR row offsets
#define O_CAA     725584     // float[50000]: rsqrt(indeg_aa+1)
#define O_CTAD    775584     // float[50000]
#define O_CATD    825584     // float[25000]
#define O_CATS    850584     // float[50000]
#define O_CTAS    900584     // float[25000]
#define O_U       925600     // float[512] (padded start)
#define O_P       926112     // float[100000]
#define O_Q       1026112    // float[100000]
#define O_R       1126112    // float[50000]
#define O_REC     1176112    // int[NB*CAP=3004416]: slabbed bucket-sorted records
#define O_CSR     4180528    // ushort[1600000] = 800000 ints

__device__ __forceinline__ float bcast(float v, int l) {
    return __int_as_float(__builtin_amdgcn_readlane(__float_as_int(v), l));
}

// ---------- fused pass 1: load edges once -> LDS bucket sort -> slab flush (+ src degrees) ----------
__global__ void __launch_bounds__(1024)
p1_fused_kernel(const int* __restrict__ src_aa, const int* __restrict__ dst_aa,
                const int* __restrict__ src_ta, const int* __restrict__ dst_ta,
                const int* __restrict__ src_at, const int* __restrict__ dst_at,
                int* __restrict__ wi) {
    __shared__ int recs[CHUNK];              // staged packed (rl<<16)|src
    __shared__ unsigned short bkt[CHUNK];    // bucket per staged edge
    __shared__ int sorted[CHUNK];            // bucket-sorted records
    __shared__ unsigned short sbkt[CHUNK];   // bucket per sorted slot
    __shared__ int cnt[NB];                  // per-bucket count
    __shared__ int cur[NB];                  // scan cursor (ends at offs+cnt)
    __shared__ int gbase[NB];                // scan buffer, then global base - offs
    int b = blockIdx.x, tid = threadIdx.x;
    int* rec_g = wi + O_REC;

    for (int i = tid; i < NB; i += 1024) cnt[i] = 0;
    __syncthreads();

    // phase A: load + stage + count (+ XCD-local src-degree atomics)
    int t0 = b * CHUNK;
    int n = min(CHUNK, TOTAL_E - t0);
    int* srch = wi + O_SRCH + (b & 7) * SRCH_STRIDE;
    for (int i = tid; i < n; i += 1024) {
        int t = t0 + i, row, s;
        if (t < EAA) {
            row = dst_aa[t]; s = src_aa[t];
        } else if (t < EAA + ETA) {
            int u = t - EAA;
            row = NA + dst_ta[u]; s = src_ta[u];
            atomicAdd(&srch[50000 + s], 1);
        } else {
            int u = t - EAA - ETA;
            row = 2 * NA + dst_at[u]; s = src_at[u];
            atomicAdd(&srch[s], 1);
        }
        int bk = row >> 8;
        recs[i] = ((row & 255) << 16) | s;
        bkt[i] = (unsigned short)bk;
        atomicAdd(&cnt[bk], 1);
    }
    __syncthreads();

    // phase B: exclusive scan of cnt -> cur (scan buffer = gbase)
    if (tid < NB) gbase[tid] = cnt[tid];
    __syncthreads();
    for (int off = 1; off < NB; off <<= 1) {
        int x = 0;
        if (tid < NB && tid >= off) x = gbase[tid - off];
        __syncthreads();
        if (tid < NB) gbase[tid] += x;
        __syncthreads();
    }
    if (tid < NB) cur[tid] = gbase[tid] - cnt[tid];   // exclusive offs
    __syncthreads();

    // phase C: place into LDS-sorted order
    for (int i = tid; i < n; i += 1024) {
        int bk = bkt[i];
        int pos = atomicAdd(&cur[bk], 1);
        sorted[pos] = recs[i];
        sbkt[pos] = (unsigned short)bk;
    }
    __syncthreads();

    // phase D: reserve global slab space per bucket; gbase = slab_base - offs
    for (int bk = tid; bk < NB; bk += 1024) {
        int len = cnt[bk];
        if (len > 0) {
            int gb = atomicAdd(&wi[O_BTOT + bk], len);
            gbase[bk] = bk * CAP + gb - (cur[bk] - len);   // cur now = offs+len
        }
    }
    __syncthreads();

    // phase E: flush contiguous runs to the slab
    for (int i = tid; i < n; i += 1024) {
        int bk = sbkt[i];
        rec_g[gbase[bk] + i] = sorted[i];
    }
}

// ---------- fused pass 2 + aux: blocks 0..NB-1 = p2 (self-computed base); NB..NB+73 = src coefs; NB+74 = U ----------
__global__ void __launch_bounds__(1024)
p2_aux_kernel(int* __restrict__ wi, float* __restrict__ wf,
              const float* __restrict__ W2_aa, const float* __restrict__ W2_ta,
              const float* __restrict__ W2_at, const float* __restrict__ b2_aa,
              const float* __restrict__ b2_ta, const float* __restrict__ b2_at,
              const float* __restrict__ Wp_a, const float* __restrict__ bp_a,
              const float* __restrict__ Wp_t, const float* __restrict__ bp_t) {
    int bb = blockIdx.x, tid = threadIdx.x, lane = tid & 63, wid = tid >> 6;
    if (bb < NB) {
        const int* rec = wi + O_REC;
        unsigned short* csr = (unsigned short*)(wi + O_CSR);
        int* ro = wi + O_RO;
        float* caa = wf + O_CAA;
        float* ctad = wf + O_CTAD;
        float* catd = wf + O_CATD;
        __shared__ int deg[256];
        __shared__ int rb[256];
        __shared__ int wsum[16];
        int k = bb;
        // self-compute g0 = sum of BTOT[0..k)
        int a = (tid < k) ? wi[O_BTOT + tid] : 0;
#pragma unroll
        for (int m = 32; m; m >>= 1) a += __shfl_xor(a, m, 64);
        if (lane == 0) wsum[wid] = a;
        if (tid < 256) deg[tid] = 0;
        __syncthreads();
        int g0 = 0;
#pragma unroll
        for (int w = 0; w < 16; ++w) g0 += wsum[w];
        int s0 = k * CAP;                       // slab base
        int len = wi[O_BTOT + k];
        for (int j = tid; j < len; j += 1024) atomicAdd(&deg[rec[s0 + j] >> 16], 1);
        __syncthreads();
        int v = 0, x = 0;
        if (tid < 256) {
            v = deg[tid];
            x = v;
#pragma unroll
            for (int off = 1; off < 64; off <<= 1) {
                int y = __shfl_up(x, off, 64);
                if (lane >= off) x += y;
            }
            if (lane == 63) wsum[wid] = x;
        }
        __syncthreads();
        if (tid < 256) {
            int wpre = 0;
            for (int w = 0; w < wid; ++w) wpre += wsum[w];
            int excl = x - v + wpre;
            rb[tid] = g0 + excl;
            int g = k * 256 + tid;
            if (g < NSEG) {
                ro[g] = g0 + excl;
                if (g < NA) caa[g] = rsqrtf((float)v + 1.0f);
                else if (g < 2 * NA) ctad[g - NA] = v > 0 ? rsqrtf((float)v) : 0.0f;
                else catd[g - 2 * NA] = v > 0 ? rsqrtf((float)v) : 0.0f;
            }
            if (k == NB - 1 && tid == 0) ro[NSEG] = TOTAL_E;
        }
        __syncthreads();
        for (int j = tid; j < len; j += 1024) {
            int rc = rec[s0 + j];
            int pos = atomicAdd(&rb[rc >> 16], 1);
            csr[pos] = (unsigned short)(rc & 0xFFFF);
        }
    } else if (bb < NB + 74) {
        int t = (bb - NB) * 1024 + tid;
        if (t < 75000) {
            int d = 0;
#pragma unroll
            for (int c = 0; c < 8; ++c) d += wi[O_SRCH + c * SRCH_STRIDE + t];
            float v = d > 0 ? rsqrtf((float)d) : 0.0f;
            if (t < 50000) wf[O_CATS + t] = v;
            else           wf[O_CTAS + (t - 50000)] = v;
        }
    } else {
        float* U = wf + O_U;
        int t = tid;
        if (t < 128) {
            int k = t >> 1, j = t & 1;
            float a = 0.f;
            for (int f = 0; f < 64; ++f) a = fmaf(W2_aa[k * 64 + f], Wp_a[f * 2 + j], a);
            U[t] = a;
        } else if (t < 256) {
            int u = t - 128; int k = u >> 1, j = u & 1;
            float a = 0.f;
            for (int f = 0; f < 64; ++f) a = fmaf(W2_ta[k * 64 + f], Wp_a[f * 2 + j], a);
            U[128 + u] = a;
        } else if (t < 384) {
            int u = t - 256; int k = u >> 1, j = u & 1;
            float a = 0.f;
            for (int f = 0; f < 64; ++f) a = fmaf(W2_at[k * 64 + f], Wp_t[f * 2 + j], a);
            U[256 + u] = a;
        } else if (t < 386) {
            int j = t - 384;
            float a = bp_a[j];
            for (int f = 0; f < 64; ++f) a = fmaf(b2_aa[f] + b2_ta[f], Wp_a[f * 2 + j], a);
            U[384 + j] = a;
        } else if (t < 388) {
            int j = t - 386;
            float a = bp_t[j];
            for (int f = 0; f < 64; ++f) a = fmaf(b2_at[f], Wp_t[f * 2 + j], a);
            U[386 + j] = a;
        }
    }
}

// ---------- conv1: PERSISTENT blocks, 1-deep software pipeline, unroll-2 gather,
//            coef-via-shfl, XOR-swizzled W (16B-aligned b128 broadcast reads) ----------
__global__ void __launch_bounds__(256, 8)
conv1_all_kernel(const float* __restrict__ x_a, const float* __restrict__ x_t,
                 const int* __restrict__ ro, const unsigned short* __restrict__ csr,
                 const float* __restrict__ c_aa, const float* __restrict__ c_ta_d,
                 const float* __restrict__ c_ta_s, const float* __restrict__ c_at_s,
                 const float* __restrict__ c_at_d,
                 const float* __restrict__ W_aa, const float* __restrict__ b_aa,
                 const float* __restrict__ W_ta, const float* __restrict__ b_ta,
                 const float* __restrict__ W_at, const float* __restrict__ b_at,
                 const float* __restrict__ U,
                 float* __restrict__ p, float* __restrict__ q, float* __restrict__ r) {
    // swizzled layout: sW[col*32 + (k ^ ((col&7)<<2))] = W[k][col]
    // -> per-g read of 4 consecutive k's is one 16B-aligned ds_read_b128;
    //    the 8 lanes sharing (lane&7) read the SAME address -> LDS broadcast, 0 conflicts
    __shared__ float sW0[64 * 32];
    __shared__ float sW1[64 * 32];
    int lane = threadIdx.x & 63;
    int wid = threadIdx.x >> 6;
    int e8 = lane >> 3, k4 = lane & 7;
    int sw = (lane & 7) << 2;

    if (blockIdx.x < NAB) {
        // ---------- agents: groups g = blockIdx.x, +NAB, ... < 12500 (node i = g*4+wid) ----------
        for (int idx = threadIdx.x; idx < 2048; idx += 256) {
            int k = idx >> 6, col = idx & 63;
            int pos = col * 32 + (k ^ ((col & 7) << 2));
            sW0[pos] = W_aa[idx];
            sW1[pos] = W_ta[idx];
        }
        __syncthreads();
        float bias = b_aa[lane] + b_ta[lane];
        float u0 = U[lane * 2], u1 = U[lane * 2 + 1];
        float u2 = U[256 + lane * 2], u3 = U[256 + lane * 2 + 1];
        const float* wbA = sW0 + lane * 32;
        const float* wbT = sW1 + lane * 32;

        int g = blockIdx.x;
        int i = g * 4 + wid;
        // prologue: current group's rows + csr + edge-coefs
        int b0 = ro[i], e0v = ro[i + 1];
        int b1 = ro[NA + i], e1v = ro[NA + i + 1];
        int na = e0v - b0, nt = e1v - b1;
        int sA = (lane < na) ? (int)csr[b0 + lane] : -1;
        int sT = (lane < nt) ? (int)csr[b1 + lane] : -1;
        float cAv = (sA >= 0) ? c_aa[sA] : 0.f;
        float cTv = (sT >= 0) ? c_ta_s[sT] : 0.f;

        while (true) {
            // (1) issue: next group's row offsets + current node coefs + self-loop row
            int gn = g + NAB;
            bool more = gn < 12500;
            int in_ = gn * 4 + wid;
            int nb0 = 0, ne0 = 0, nb1 = 0, ne1 = 0;
            if (more) {
                nb0 = ro[in_]; ne0 = ro[in_ + 1];
                nb1 = ro[NA + in_]; ne1 = ro[NA + in_ + 1];
            }
            float ci = c_aa[i], ctd = c_ta_d[i], cq = c_at_s[i];
            float4 xs = make_float4(0.f, 0.f, 0.f, 0.f);
            if (e8 == 0) xs = *(const float4*)(x_a + (size_t)i * 32 + k4 * 4);

            // (2) gathers for current group (unroll-2: two x rows in flight)
            float4 accA = make_float4(0.f, 0.f, 0.f, 0.f);
            float4 accT = make_float4(0.f, 0.f, 0.f, 0.f);
            int nGA = (min(na, 64) + 7) >> 3;
            int nGT = (min(nt, 64) + 7) >> 3;
            int ga = 0;
            for (; ga + 2 <= nGA; ga += 2) {
                int s0 = __shfl(sA, ga * 8 + e8, 64);
                int s1 = __shfl(sA, ga * 8 + 8 + e8, 64);
                float w0 = __shfl(cAv, ga * 8 + e8, 64);
                float w1 = __shfl(cAv, ga * 8 + 8 + e8, 64);
                float4 x0 = make_float4(0.f, 0.f, 0.f, 0.f), x1 = x0;
                if (s0 >= 0) x0 = *(const float4*)(x_a + (size_t)s0 * 32 + k4 * 4);
                if (s1 >= 0) x1 = *(const float4*)(x_a + (size_t)s1 * 32 + k4 * 4);
                accA.x = fmaf(x0.x, w0, accA.x); accA.y = fmaf(x0.y, w0, accA.y);
                accA.z = fmaf(x0.z, w0, accA.z); accA.w = fmaf(x0.w, w0, accA.w);
                accA.x = fmaf(x1.x, w1, accA.x); accA.y = fmaf(x1.y, w1, accA.y);
                accA.z = fmaf(x1.z, w1, accA.z); accA.w = fmaf(x1.w, w1, accA.w);
            }
            if (ga < nGA) {
                int s0 = __shfl(sA, ga * 8 + e8, 64);
                float w0 = __shfl(cAv, ga * 8 + e8, 64);
                float4 x0 = make_float4(0.f, 0.f, 0.f, 0.f);
                if (s0 >= 0) x0 = *(const float4*)(x_a + (size_t)s0 * 32 + k4 * 4);
                accA.x = fmaf(x0.x, w0, accA.x); accA.y = fmaf(x0.y, w0, accA.y);
                accA.z = fmaf(x0.z, w0, accA.z); accA.w = fmaf(x0.w, w0, accA.w);
            }
            for (int j = b0 + 64 + e8; j < e0v; j += 8) {   // rare tail
                int s = csr[j];
                float w = c_aa[s];
                float4 xv = *(const float4*)(x_a + (size_t)s * 32 + k4 * 4);
                accA.x = fmaf(xv.x, w, accA.x); accA.y = fmaf(xv.y, w, accA.y);
                accA.z = fmaf(xv.z, w, accA.z); accA.w = fmaf(xv.w, w, accA.w);
            }
            int gt = 0;
            for (; gt + 2 <= nGT; gt += 2) {
                int s0 = __shfl(sT, gt * 8 + e8, 64);
                int s1 = __shfl(sT, gt * 8 + 8 + e8, 64);
                float w0 = __shfl(cTv, gt * 8 + e8, 64);
                float w1 = __shfl(cTv, gt * 8 + 8 + e8, 64);
                float4 x0 = make_float4(0.f, 0.f, 0.f, 0.f), x1 = x0;
                if (s0 >= 0) x0 = *(const float4*)(x_t + (size_t)s0 * 32 + k4 * 4);
                if (s1 >= 0) x1 = *(const float4*)(x_t + (size_t)s1 * 32 + k4 * 4);
                accT.x = fmaf(x0.x, w0, accT.x); accT.y = fmaf(x0.y, w0, accT.y);
                accT.z = fmaf(x0.z, w0, accT.z); accT.w = fmaf(x0.w, w0, accT.w);
                accT.x = fmaf(x1.x, w1, accT.x); accT.y = fmaf(x1.y, w1, accT.y);
                accT.z = fmaf(x1.z, w1, accT.z); accT.w = fmaf(x1.w, w1, accT.w);
            }
            if (gt < nGT) {
                int s0 = __shfl(sT, gt * 8 + e8, 64);
                float w0 = __shfl(cTv, gt * 8 + e8, 64);
                float4 x0 = make_float4(0.f, 0.f, 0.f, 0.f);
                if (s0 >= 0) x0 = *(const float4*)(x_t + (size_t)s0 * 32 + k4 * 4);
                accT.x = fmaf(x0.x, w0, accT.x); accT.y = fmaf(x0.y, w0, accT.y);
                accT.z = fmaf(x0.z, w0, accT.z); accT.w = fmaf(x0.w, w0, accT.w);
            }
            for (int j = b1 + 64 + e8; j < e1v; j += 8) {   // rare tail
                int s = csr[j];
                float w = c_ta_s[s];
                float4 xv = *(const float4*)(x_t + (size_t)s * 32 + k4 * 4);
                accT.x = fmaf(xv.x, w, accT.x); accT.y = fmaf(xv.y, w, accT.y);
                accT.z = fmaf(xv.z, w, accT.z); accT.w = fmaf(xv.w, w, accT.w);
            }
            // self-loop
            accA.x = fmaf(xs.x, ci, accA.x); accA.y = fmaf(xs.y, ci, accA.y);
            accA.z = fmaf(xs.z, ci, accA.z); accA.w = fmaf(xs.w, ci, accA.w);

            // (3) issue: next group's csr preload (latency covered by matvec below)
            int nsA = -1, nsT = -1;
            if (more) {
                int nna = ne0 - nb0, nnt = ne1 - nb1;
                nsA = (lane < nna) ? (int)csr[nb0 + lane] : -1;
                nsT = (lane < nnt) ? (int)csr[nb1 + lane] : -1;
            }

            // (4) reduce across e8 groups + matvec
#pragma unroll
            for (int m = 8; m <= 32; m <<= 1) {
                accA.x += __shfl_xor(accA.x, m, 64);
                accA.y += __shfl_xor(accA.y, m, 64);
                accA.z += __shfl_xor(accA.z, m, 64);
                accA.w += __shfl_xor(accA.w, m, 64);
                accT.x += __shfl_xor(accT.x, m, 64);
                accT.y += __shfl_xor(accT.y, m, 64);
                accT.z += __shfl_xor(accT.z, m, 64);
                accT.w += __shfl_xor(accT.w, m, 64);
            }
            float hA = 0.f, hT = 0.f;
#pragma unroll
            for (int g2 = 0; g2 < 8; ++g2) {
                float a0 = bcast(accA.x, g2), a1 = bcast(accA.y, g2);
                float a2 = bcast(accA.z, g2), a3 = bcast(accA.w, g2);
                float t0 = bcast(accT.x, g2), t1 = bcast(accT.y, g2);
                float t2 = bcast(accT.z, g2), t3 = bcast(accT.w, g2);
                int off = (g2 * 4) ^ sw;
                float4 wa = *(const float4*)(wbA + off);
                float4 wt = *(const float4*)(wbT + off);
                hA = fmaf(a0, wa.x, hA); hA = fmaf(a1, wa.y, hA);
                hA = fmaf(a2, wa.z, hA); hA = fmaf(a3, wa.w, hA);
                hT = fmaf(t0, wt.x, hT); hT = fmaf(t1, wt.y, hT);
                hT = fmaf(t2, wt.z, hT); hT = fmaf(t3, wt.w, hT);
            }

            // (5) issue: next group's edge-coef gathers (csr has landed by now)
            float ncA = 0.f, ncT = 0.f;
            if (more) {
                ncA = (nsA >= 0) ? c_aa[nsA] : 0.f;
                ncT = (nsT >= 0) ? c_ta_s[nsT] : 0.f;
            }

            // (6) finish current node: relu, fused projection, store
            float h = fmaxf(bias + ci * hA + c_ta_d[i] * hT, 0.f);
            (void)ctd; // ctd == c_ta_d[i], loaded early; keep the early issue
            h = fmaxf(bias + ci * hA + ctd * hT, 0.f);
            float p0 = h * u0, p1 = h * u1;
            float q0 = h * u2, q1 = h * u3;
#pragma unroll
            for (int m = 32; m; m >>= 1) {
                p0 += __shfl_xor(p0, m, 64);
                p1 += __shfl_xor(p1, m, 64);
                q0 += __shfl_xor(q0, m, 64);
                q1 += __shfl_xor(q1, m, 64);
            }
            if (lane == 0) {
                *(float2*)&p[i * 2] = make_float2(p0 * ci, p1 * ci);
                *(float2*)&q[i * 2] = make_float2(q0 * cq, q1 * cq);
            }

            if (!more) break;
            // (7) rotate pipeline state
            g = gn; i = in_;
            b0 = nb0; e0v = ne0; b1 = nb1; e1v = ne1;
            na = ne0 - nb0; nt = ne1 - nb1;
            sA = nsA; sT = nsT; cAv = ncA; cTv = ncT;
        }
    } else {
        // ---------- targets: groups g = blockIdx.x-NAB, +NTB, ... < 6250 ----------
        for (int idx = threadIdx.x; idx < 2048; idx += 256) {
            int k = idx >> 6, col = idx & 63;
            sW0[col * 32 + (k ^ ((col & 7) << 2))] = W_at[idx];
        }
        __syncthreads();
        float bias = b_at[lane];
        float u0 = U[128 + lane * 2], u1 = U[128 + lane * 2 + 1];
        const float* wbA = sW0 + lane * 32;

        int g = blockIdx.x - NAB;
        int i = g * 4 + wid;
        int b0 = ro[2 * NA + i], e0v = ro[2 * NA + i + 1];
        int na = e0v - b0;
        int sA = (lane < na) ? (int)csr[b0 + lane] : -1;
        float cAv = (sA >= 0) ? c_at_s[sA] : 0.f;

        while (true) {
            int gn = g + NTB;
            bool more = gn < 6250;
            int in_ = gn * 4 + wid;
            int nb0 = 0, ne0 = 0;
            if (more) { nb0 = ro[2 * NA + in_]; ne0 = ro[2 * NA + in_ + 1]; }
            float cd = c_at_d[i], cr = c_ta_s[i];

            float4 acc = make_float4(0.f, 0.f, 0.f, 0.f);
            int nG = (min(na, 64) + 7) >> 3;
            int ga = 0;
            for (; ga + 2 <= nG; ga += 2) {
                int s0 = __shfl(sA, ga * 8 + e8, 64);
                int s1 = __shfl(sA, ga * 8 + 8 + e8, 64);
                float w0 = __shfl(cAv, ga * 8 + e8, 64);
                float w1 = __shfl(cAv, ga * 8 + 8 + e8, 64);
                float4 x0 = make_float4(0.f, 0.f, 0.f, 0.f), x1 = x0;
                if (s0 >= 0) x0 = *(const float4*)(x_a + (size_t)s0 * 32 + k4 * 4);
                if (s1 >= 0) x1 = *(const float4*)(x_a + (size_t)s1 * 32 + k4 * 4);
                acc.x = fmaf(x0.x, w0, acc.x); acc.y = fmaf(x0.y, w0, acc.y);
                acc.z = fmaf(x0.z, w0, acc.z); acc.w = fmaf(x0.w, w0, acc.w);
                acc.x = fmaf(x1.x, w1, acc.x); acc.y = fmaf(x1.y, w1, acc.y);
                acc.z = fmaf(x1.z, w1, acc.z); acc.w = fmaf(x1.w, w1, acc.w);
            }
            if (ga < nG) {
                int s0 = __shfl(sA, ga * 8 + e8, 64);
                float w0 = __shfl(cAv, ga * 8 + e8, 64);
                float4 x0 = make_float4(0.f, 0.f, 0.f, 0.f);
                if (s0 >= 0) x0 = *(const float4*)(x_a + (size_t)s0 * 32 + k4 * 4);
                acc.x = fmaf(x0.x, w0, acc.x); acc.y = fmaf(x0.y, w0, acc.y);
                acc.z = fmaf(x0.z, w0, acc.z); acc.w = fmaf(x0.w, w0, acc.w);
            }
            for (int j = b0 + 64 + e8; j < e0v; j += 8) {   // rare tail
                int s = csr[j];
                float w = c_at_s[s];
                float4 xv = *(const float4*)(x_a + (size_t)s * 32 + k4 * 4);
                acc.x = fmaf(xv.x, w, acc.x); acc.y = fmaf(xv.y, w, acc.y);
                acc.z = fmaf(xv.z, w, acc.z); acc.w = fmaf(xv.w, w, acc.w);
            }

            int nsA = -1;
            if (more) {
                int nna = ne0 - nb0;
                nsA = (lane < nna) ? (int)csr[nb0 + lane] : -1;
            }

#pragma unroll
            for (int m = 8; m <= 32; m <<= 1) {
                acc.x += __shfl_xor(acc.x, m, 64);
                acc.y += __shfl_xor(acc.y, m, 64);
                acc.z += __shfl_xor(acc.z, m, 64);
                acc.w += __shfl_xor(acc.w, m, 64);
            }
            float hA = 0.f;
#pragma unroll
            for (int g2 = 0; g2 < 8; ++g2) {
                float a0 = bcast(acc.x, g2), a1 = bcast(acc.y, g2);
                float a2 = bcast(acc.z, g2), a3 = bcast(acc.w, g2);
                float4 wa = *(const float4*)(wbA + ((g2 * 4) ^ sw));
                hA = fmaf(a0, wa.x, hA); hA = fmaf(a1, wa.y, hA);
                hA = fmaf(a2, wa.z, hA); hA = fmaf(a3, wa.w, hA);
            }

            float ncA = 0.f;
            if (more) ncA = (nsA >= 0) ? c_at_s[nsA] : 0.f;

            float h = fmaxf(bias + cd * hA, 0.f);
            float r0 = h * u0, r1 = h * u1;
#pragma unroll
            for (int m = 32; m; m >>= 1) {
                r0 += __shfl_xor(r0, m, 64);
                r1 += __shfl_xor(r1, m, 64);
            }
            if (lane == 0) {
                *(float2*)&r[i * 2] = make_float2(r0 * cr, r1 * cr);
            }

            if (!more) break;
            g = gn; i = in_;
            b0 = nb0; e0v = ne0; na = ne0 - nb0;
            sA = nsA; cAv = ncA;
        }
    }
}

// ---------- conv2+proj: one wave per node, 32 edge slots x 2 comps ----------
__global__ void __launch_bounds__(256)
out_all_kernel(const float* __restrict__ p, const float* __restrict__ q,
               const float* __restrict__ r, const int* __restrict__ ro,
               const unsigned short* __restrict__ csr,
               const float* __restrict__ c_aa, const float* __restrict__ c_ta_d,
               const float* __restrict__ c_at_d, const float* __restrict__ U,
               float* __restrict__ out) {
    int wgid = blockIdx.x * 4 + (threadIdx.x >> 6);
    int lane = threadIdx.x & 63;
    int slot = lane >> 1, j = lane & 1;
    if (wgid < NA) {
        int i = wgid;
        int b0 = ro[i], n0 = ro[i + 1] - b0;
        float accA = (slot == 0) ? p[i * 2 + j] : 0.f;   // self-loop (p premultiplied)
        for (int e = slot; e < n0; e += 32) accA += p[(int)csr[b0 + e] * 2 + j];
        int b1 = ro[NA + i], n1 = ro[NA + i + 1] - b1;
        float accT = 0.f;
        for (int e = slot; e < n1; e += 32) accT += r[(int)csr[b1 + e] * 2 + j];
#pragma unroll
        for (int m = 2; m <= 32; m <<= 1) {
            accA += __shfl_xor(accA, m, 64);
            accT += __shfl_xor(accT, m, 64);
        }
        if (lane < 2) out[i * 2 + j] = U[384 + j] + accA * c_aa[i] + accT * c_ta_d[i];
    } else {
        int i = wgid - NA;
        int b0 = ro[2 * NA + i], n0 = ro[2 * NA + i + 1] - b0;
        float acc = 0.f;
        for (int e = slot; e < n0; e += 32) acc += q[(int)csr[b0 + e] * 2 + j];
#pragma unroll
        for (int m = 2; m <= 32; m <<= 1) acc += __shfl_xor(acc, m, 64);
        if (lane < 2) out[NA * 2 + i * 2 + j] = U[386 + j] + acc * c_at_d[i];
    }
}

extern "C" void kernel_launch(void* const* d_in, const int* in_sizes, int n_in,
                              void* d_out, int out_size, void* d_ws, size_t ws_size,
                              hipStream_t stream) {
    const float* x_a   = (const float*)d_in[1];
    const float* x_t   = (const float*)d_in[2];
    const int* src_aa  = (const int*)d_in[3];
    const int* dst_aa  = (const int*)d_in[4];
    const int* src_at  = (const int*)d_in[5];
    const int* dst_at  = (const int*)d_in[6];
    const int* src_ta  = (const int*)d_in[7];
    const int* dst_ta  = (const int*)d_in[8];
    const float* W1_aa = (const float*)d_in[9];
    const float* b1_aa = (const float*)d_in[10];
    const float* W1_at = (const float*)d_in[11];
    const float* b1_at = (const float*)d_in[12];
    const float* W1_ta = (const float*)d_in[13];
    const float* b1_ta = (const float*)d_in[14];
    const float* W2_aa = (const float*)d_in[15];
    const float* b2_aa = (const float*)d_in[16];
    const float* W2_at = (const float*)d_in[17];
    const float* b2_at = (const float*)d_in[18];
    const float* W2_ta = (const float*)d_in[19];
    const float* b2_ta = (const float*)d_in[20];
    const float* Wp_a  = (const float*)d_in[21];
    const float* bp_a  = (const float*)d_in[22];
    const float* Wp_t  = (const float*)d_in[23];
    const float* bp_t  = (const float*)d_in[24];

    int*   wi  = (int*)d_ws;
    float* wf  = (float*)d_ws;
    unsigned short* csr = (unsigned short*)(wi + O_CSR);
    float* out = (float*)d_out;

    // single memset: 8-copy src-degree histograms + adjacent bucket totals
    hipMemsetAsync(wi + O_SRCH, 0, (size_t)(8 * SRCH_STRIDE + 512) * 4, stream);

    // fused pass 1: single edge read -> LDS bucket sort -> slab flush (+ src degrees)
    p1_fused_kernel<<<NBLK1, 1024, 0, stream>>>(src_aa, dst_aa, src_ta, dst_ta,
                                                src_at, dst_at, wi);

    // fused pass 2 + aux: p2 (self-computed bases) | src coefs | U fuse
    p2_aux_kernel<<<NB + 75, 1024, 0, stream>>>(wi, wf, W2_aa, W2_ta, W2_at,
                                                b2_aa, b2_ta, b2_at,
                                                Wp_a, bp_a, Wp_t, bp_t);

    // conv1: persistent 8 blocks/CU, pipelined groups
    conv1_all_kernel<<<NAB + NTB, 256, 0, stream>>>(
        x_a, x_t, wi + O_RO, csr,
        wf + O_CAA, wf + O_CTAD, wf + O_CTAS, wf + O_CATS, wf + O_CATD,
        W1_aa, b1_aa, W1_ta, b1_ta, W1_at, b1_at, wf + O_U,
        wf + O_P, wf + O_Q, wf + O_R);

    // conv2 + projection, wave per node
    out_all_kernel<<<(NA + NT) / 4, 256, 0, stream>>>(
        wf + O_P, wf + O_Q, wf + O_R, wi + O_RO, csr,
        wf + O_CAA, wf + O_CTAD, wf + O_CATD, wf + O_U, out);
}

// Round 2
// 247.735 us; speedup vs baseline: 1.6359x; 1.6359x over previous
//
#include <hip/hip_runtime.h>

#define NA 50000
#define NT 25000
#define EAA 800000
#define EAT 400000
#define ETA 400000
#define NSEG 125000          // NA + NA + NT rows: [aa | ta | at]
#define TOTAL_E 1600000
#define NB 489               // coarse buckets of 256 rows
#define NBLK1 391            // pass-1 blocks
#define CHUNK 4096           // edges per pass-1 block
#define CAP 6144             // REC slab capacity per bucket (max observed bucket ~4800)
#define SRCH_STRIDE 75008    // per-copy src-histogram stride: at[50000] | ta[25000] | pad

// conv1 persistent grid: 2048 blocks
#define NAB 1564             // agent blocks: 12500 groups -> 8 (or 7) groups/block
#define NTB 484              // target blocks: 6250 groups -> 13 (or 12) groups/block

// ---- workspace layout (4-byte element offsets) ----
#define O_SRCH    0          // int[8*75008]: 8 XCD-local src-degree histogram copies
#define O_BTOT    600064     // int[512]: per-bucket totals (adjacent to SRCH -> single memset)
#define O_RO      600576     // int[125001]: CSR row offsets
#define O_CAA     725584     // float[50000]: rsqrt(indeg_aa+1)
#define O_CTAD    775584     // float[50000]
#define O_CATD    825584     // float[25000]
#define O_CATS    850584     // float[50000]
#define O_CTAS    900584     // float[25000]
#define O_U       925600     // float[512] (padded start)
#define O_P       926112     // float[100000]
#define O_Q       1026112    // float[100000]
#define O_R       1126112    // float[50000]
#define O_REC     1176112    // int[NB*CAP=3004416]: slabbed bucket-sorted records
#define O_CSR     4180528    // ushort[1600000] = 800000 ints

__device__ __forceinline__ float bcast(float v, int l) {
    return __int_as_float(__builtin_amdgcn_readlane(__float_as_int(v), l));
}

// ---------- fused pass 1: load edges once -> LDS bucket sort -> slab flush (+ src degrees) ----------
__global__ void __launch_bounds__(1024)
p1_fused_kernel(const int* __restrict__ src_aa, const int* __restrict__ dst_aa,
                const int* __restrict__ src_ta, const int* __restrict__ dst_ta,
                const int* __restrict__ src_at, const int* __restrict__ dst_at,
                int* __restrict__ wi) {
    __shared__ int recs[CHUNK];              // staged packed (rl<<16)|src
    __shared__ unsigned short bkt[CHUNK];    // bucket per staged edge
    __shared__ int sorted[CHUNK];            // bucket-sorted records
    __shared__ unsigned short sbkt[CHUNK];   // bucket per sorted slot
    __shared__ int cnt[NB];                  // per-bucket count
    __shared__ int cur[NB];                  // scan cursor (ends at offs+cnt)
    __shared__ int gbase[NB];                // scan buffer, then global base - offs
    int b = blockIdx.x, tid = threadIdx.x;
    int* rec_g = wi + O_REC;

    for (int i = tid; i < NB; i += 1024) cnt[i] = 0;
    __syncthreads();

    // phase A: load + stage + count (+ XCD-local src-degree atomics)
    int t0 = b * CHUNK;
    int n = min(CHUNK, TOTAL_E - t0);
    int* srch = wi + O_SRCH + (b & 7) * SRCH_STRIDE;
    for (int i = tid; i < n; i += 1024) {
        int t = t0 + i, row, s;
        if (t < EAA) {
            row = dst_aa[t]; s = src_aa[t];
        } else if (t < EAA + ETA) {
            int u = t - EAA;
            row = NA + dst_ta[u]; s = src_ta[u];
            atomicAdd(&srch[50000 + s], 1);
        } else {
            int u = t - EAA - ETA;
            row = 2 * NA + dst_at[u]; s = src_at[u];
            atomicAdd(&srch[s], 1);
        }
        int bk = row >> 8;
        recs[i] = ((row & 255) << 16) | s;
        bkt[i] = (unsigned short)bk;
        atomicAdd(&cnt[bk], 1);
    }
    __syncthreads();

    // phase B: exclusive scan of cnt -> cur (scan buffer = gbase)
    if (tid < NB) gbase[tid] = cnt[tid];
    __syncthreads();
    for (int off = 1; off < NB; off <<= 1) {
        int x = 0;
        if (tid < NB && tid >= off) x = gbase[tid - off];
        __syncthreads();
        if (tid < NB) gbase[tid] += x;
        __syncthreads();
    }
    if (tid < NB) cur[tid] = gbase[tid] - cnt[tid];   // exclusive offs
    __syncthreads();

    // phase C: place into LDS-sorted order
    for (int i = tid; i < n; i += 1024) {
        int bk = bkt[i];
        int pos = atomicAdd(&cur[bk], 1);
        sorted[pos] = recs[i];
        sbkt[pos] = (unsigned short)bk;
    }
    __syncthreads();

    // phase D: reserve global slab space per bucket; gbase = slab_base - offs
    for (int bk = tid; bk < NB; bk += 1024) {
        int len = cnt[bk];
        if (len > 0) {
            int gb = atomicAdd(&wi[O_BTOT + bk], len);
            gbase[bk] = bk * CAP + gb - (cur[bk] - len);   // cur now = offs+len
        }
    }
    __syncthreads();

    // phase E: flush contiguous runs to the slab
    for (int i = tid; i < n; i += 1024) {
        int bk = sbkt[i];
        rec_g[gbase[bk] + i] = sorted[i];
    }
}

// ---------- fused pass 2 + aux: blocks 0..NB-1 = p2 (self-computed base); NB..NB+73 = src coefs; NB+74 = U ----------
__global__ void __launch_bounds__(1024)
p2_aux_kernel(int* __restrict__ wi, float* __restrict__ wf,
              const float* __restrict__ W2_aa, const float* __restrict__ W2_ta,
              const float* __restrict__ W2_at, const float* __restrict__ b2_aa,
              const float* __restrict__ b2_ta, const float* __restrict__ b2_at,
              const float* __restrict__ Wp_a, const float* __restrict__ bp_a,
              const float* __restrict__ Wp_t, const float* __restrict__ bp_t) {
    int bb = blockIdx.x, tid = threadIdx.x, lane = tid & 63, wid = tid >> 6;
    if (bb < NB) {
        const int* rec = wi + O_REC;
        unsigned short* csr = (unsigned short*)(wi + O_CSR);
        int* ro = wi + O_RO;
        float* caa = wf + O_CAA;
        float* ctad = wf + O_CTAD;
        float* catd = wf + O_CATD;
        __shared__ int deg[256];
        __shared__ int rb[256];
        __shared__ int wsum[16];
        int k = bb;
        // self-compute g0 = sum of BTOT[0..k)
        int a = (tid < k) ? wi[O_BTOT + tid] : 0;
#pragma unroll
        for (int m = 32; m; m >>= 1) a += __shfl_xor(a, m, 64);
        if (lane == 0) wsum[wid] = a;
        if (tid < 256) deg[tid] = 0;
        __syncthreads();
        int g0 = 0;
#pragma unroll
        for (int w = 0; w < 16; ++w) g0 += wsum[w];
        int s0 = k * CAP;                       // slab base
        int len = wi[O_BTOT + k];
        for (int j = tid; j < len; j += 1024) atomicAdd(&deg[rec[s0 + j] >> 16], 1);
        __syncthreads();
        int v = 0, x = 0;
        if (tid < 256) {
            v = deg[tid];
            x = v;
#pragma unroll
            for (int off = 1; off < 64; off <<= 1) {
                int y = __shfl_up(x, off, 64);
                if (lane >= off) x += y;
            }
            if (lane == 63) wsum[wid] = x;
        }
        __syncthreads();
        if (tid < 256) {
            int wpre = 0;
            for (int w = 0; w < wid; ++w) wpre += wsum[w];
            int excl = x - v + wpre;
            rb[tid] = g0 + excl;
            int g = k * 256 + tid;
            if (g < NSEG) {
                ro[g] = g0 + excl;
                if (g < NA) caa[g] = rsqrtf((float)v + 1.0f);
                else if (g < 2 * NA) ctad[g - NA] = v > 0 ? rsqrtf((float)v) : 0.0f;
                else catd[g - 2 * NA] = v > 0 ? rsqrtf((float)v) : 0.0f;
            }
            if (k == NB - 1 && tid == 0) ro[NSEG] = TOTAL_E;
        }
        __syncthreads();
        for (int j = tid; j < len; j += 1024) {
            int rc = rec[s0 + j];
            int pos = atomicAdd(&rb[rc >> 16], 1);
            csr[pos] = (unsigned short)(rc & 0xFFFF);
        }
    } else if (bb < NB + 74) {
        int t = (bb - NB) * 1024 + tid;
        if (t < 75000) {
            int d = 0;
#pragma unroll
            for (int c = 0; c < 8; ++c) d += wi[O_SRCH + c * SRCH_STRIDE + t];
            float v = d > 0 ? rsqrtf((float)d) : 0.0f;
            if (t < 50000) wf[O_CATS + t] = v;
            else           wf[O_CTAS + (t - 50000)] = v;
        }
    } else {
        float* U = wf + O_U;
        int t = tid;
        if (t < 128) {
            int k = t >> 1, j = t & 1;
            float a = 0.f;
            for (int f = 0; f < 64; ++f) a = fmaf(W2_aa[k * 64 + f], Wp_a[f * 2 + j], a);
            U[t] = a;
        } else if (t < 256) {
            int u = t - 128; int k = u >> 1, j = u & 1;
            float a = 0.f;
            for (int f = 0; f < 64; ++f) a = fmaf(W2_ta[k * 64 + f], Wp_a[f * 2 + j], a);
            U[128 + u] = a;
        } else if (t < 384) {
            int u = t - 256; int k = u >> 1, j = u & 1;
            float a = 0.f;
            for (int f = 0; f < 64; ++f) a = fmaf(W2_at[k * 64 + f], Wp_t[f * 2 + j], a);
            U[256 + u] = a;
        } else if (t < 386) {
            int j = t - 384;
            float a = bp_a[j];
            for (int f = 0; f < 64; ++f) a = fmaf(b2_aa[f] + b2_ta[f], Wp_a[f * 2 + j], a);
            U[384 + j] = a;
        } else if (t < 388) {
            int j = t - 386;
            float a = bp_t[j];
            for (int f = 0; f < 64; ++f) a = fmaf(b2_at[f], Wp_t[f * 2 + j], a);
            U[386 + j] = a;
        }
    }
}

// ---------- conv1: persistent blocks + 1-deep pipeline + unroll-2 gather + coef-via-shfl.
//            W in LDS: transposed, stride 33 (2-way bank alias = free; proven 0-conflict).
//            NO aggressive launch_bounds: R1's (256,8) capped VGPRs at 64 -> scratch spill
//            (WRITE_SIZE 977KB -> 188MB). (256,4) leaves 128 VGPRs: pipeline fits. ----------
__global__ void __launch_bounds__(256, 4)
conv1_all_kernel(const float* __restrict__ x_a, const float* __restrict__ x_t,
                 const int* __restrict__ ro, const unsigned short* __restrict__ csr,
                 const float* __restrict__ c_aa, const float* __restrict__ c_ta_d,
                 const float* __restrict__ c_ta_s, const float* __restrict__ c_at_s,
                 const float* __restrict__ c_at_d,
                 const float* __restrict__ W_aa, const float* __restrict__ b_aa,
                 const float* __restrict__ W_ta, const float* __restrict__ b_ta,
                 const float* __restrict__ W_at, const float* __restrict__ b_at,
                 const float* __restrict__ U,
                 float* __restrict__ p, float* __restrict__ q, float* __restrict__ r) {
    __shared__ float sW0[64 * 33];   // sW[col*33 + k] = W[k][col]
    __shared__ float sW1[64 * 33];
    int lane = threadIdx.x & 63;
    int wid = threadIdx.x >> 6;
    int e8 = lane >> 3, k4 = lane & 7;

    if (blockIdx.x < NAB) {
        // ---------- agents: groups g = blockIdx.x, +NAB, ... < 12500 (node i = g*4+wid) ----------
        for (int idx = threadIdx.x; idx < 2048; idx += 256) {
            int k = idx >> 6, col = idx & 63;
            sW0[col * 33 + k] = W_aa[idx];
            sW1[col * 33 + k] = W_ta[idx];
        }
        __syncthreads();
        float bias = b_aa[lane] + b_ta[lane];
        float u0 = U[lane * 2], u1 = U[lane * 2 + 1];
        float u2 = U[256 + lane * 2], u3 = U[256 + lane * 2 + 1];
        const float* wbA = sW0 + lane * 33;
        const float* wbT = sW1 + lane * 33;

        int g = blockIdx.x;
        int i = g * 4 + wid;
        // prologue: current group's rows + csr + edge-coefs
        int b0 = ro[i], e0v = ro[i + 1];
        int b1 = ro[NA + i], e1v = ro[NA + i + 1];
        int na = e0v - b0, nt = e1v - b1;
        int sA = (lane < na) ? (int)csr[b0 + lane] : -1;
        int sT = (lane < nt) ? (int)csr[b1 + lane] : -1;
        float cAv = (sA >= 0) ? c_aa[sA] : 0.f;
        float cTv = (sT >= 0) ? c_ta_s[sT] : 0.f;

        while (true) {
            // (1) issue: next group's row offsets + current node coefs + self-loop row
            int gn = g + NAB;
            bool more = gn < 12500;
            int in_ = gn * 4 + wid;
            int nb0 = 0, ne0 = 0, nb1 = 0, ne1 = 0;
            if (more) {
                nb0 = ro[in_]; ne0 = ro[in_ + 1];
                nb1 = ro[NA + in_]; ne1 = ro[NA + in_ + 1];
            }
            float ci = c_aa[i], ctd = c_ta_d[i], cq = c_at_s[i];
            float4 xs = make_float4(0.f, 0.f, 0.f, 0.f);
            if (e8 == 0) xs = *(const float4*)(x_a + (size_t)i * 32 + k4 * 4);

            // (2) gathers for current group (unroll-2: two x rows in flight)
            float4 accA = make_float4(0.f, 0.f, 0.f, 0.f);
            float4 accT = make_float4(0.f, 0.f, 0.f, 0.f);
            int nGA = (min(na, 64) + 7) >> 3;
            int nGT = (min(nt, 64) + 7) >> 3;
            int ga = 0;
            for (; ga + 2 <= nGA; ga += 2) {
                int s0 = __shfl(sA, ga * 8 + e8, 64);
                int s1 = __shfl(sA, ga * 8 + 8 + e8, 64);
                float w0 = __shfl(cAv, ga * 8 + e8, 64);
                float w1 = __shfl(cAv, ga * 8 + 8 + e8, 64);
                float4 x0 = make_float4(0.f, 0.f, 0.f, 0.f), x1 = x0;
                if (s0 >= 0) x0 = *(const float4*)(x_a + (size_t)s0 * 32 + k4 * 4);
                if (s1 >= 0) x1 = *(const float4*)(x_a + (size_t)s1 * 32 + k4 * 4);
                accA.x = fmaf(x0.x, w0, accA.x); accA.y = fmaf(x0.y, w0, accA.y);
                accA.z = fmaf(x0.z, w0, accA.z); accA.w = fmaf(x0.w, w0, accA.w);
                accA.x = fmaf(x1.x, w1, accA.x); accA.y = fmaf(x1.y, w1, accA.y);
                accA.z = fmaf(x1.z, w1, accA.z); accA.w = fmaf(x1.w, w1, accA.w);
            }
            if (ga < nGA) {
                int s0 = __shfl(sA, ga * 8 + e8, 64);
                float w0 = __shfl(cAv, ga * 8 + e8, 64);
                float4 x0 = make_float4(0.f, 0.f, 0.f, 0.f);
                if (s0 >= 0) x0 = *(const float4*)(x_a + (size_t)s0 * 32 + k4 * 4);
                accA.x = fmaf(x0.x, w0, accA.x); accA.y = fmaf(x0.y, w0, accA.y);
                accA.z = fmaf(x0.z, w0, accA.z); accA.w = fmaf(x0.w, w0, accA.w);
            }
            for (int j = b0 + 64 + e8; j < e0v; j += 8) {   // rare tail
                int s = csr[j];
                float w = c_aa[s];
                float4 xv = *(const float4*)(x_a + (size_t)s * 32 + k4 * 4);
                accA.x = fmaf(xv.x, w, accA.x); accA.y = fmaf(xv.y, w, accA.y);
                accA.z = fmaf(xv.z, w, accA.z); accA.w = fmaf(xv.w, w, accA.w);
            }
            int gt = 0;
            for (; gt + 2 <= nGT; gt += 2) {
                int s0 = __shfl(sT, gt * 8 + e8, 64);
                int s1 = __shfl(sT, gt * 8 + 8 + e8, 64);
                float w0 = __shfl(cTv, gt * 8 + e8, 64);
                float w1 = __shfl(cTv, gt * 8 + 8 + e8, 64);
                float4 x0 = make_float4(0.f, 0.f, 0.f, 0.f), x1 = x0;
                if (s0 >= 0) x0 = *(const float4*)(x_t + (size_t)s0 * 32 + k4 * 4);
                if (s1 >= 0) x1 = *(const float4*)(x_t + (size_t)s1 * 32 + k4 * 4);
                accT.x = fmaf(x0.x, w0, accT.x); accT.y = fmaf(x0.y, w0, accT.y);
                accT.z = fmaf(x0.z, w0, accT.z); accT.w = fmaf(x0.w, w0, accT.w);
                accT.x = fmaf(x1.x, w1, accT.x); accT.y = fmaf(x1.y, w1, accT.y);
                accT.z = fmaf(x1.z, w1, accT.z); accT.w = fmaf(x1.w, w1, accT.w);
            }
            if (gt < nGT) {
                int s0 = __shfl(sT, gt * 8 + e8, 64);
                float w0 = __shfl(cTv, gt * 8 + e8, 64);
                float4 x0 = make_float4(0.f, 0.f, 0.f, 0.f);
                if (s0 >= 0) x0 = *(const float4*)(x_t + (size_t)s0 * 32 + k4 * 4);
                accT.x = fmaf(x0.x, w0, accT.x); accT.y = fmaf(x0.y, w0, accT.y);
                accT.z = fmaf(x0.z, w0, accT.z); accT.w = fmaf(x0.w, w0, accT.w);
            }
            for (int j = b1 + 64 + e8; j < e1v; j += 8) {   // rare tail
                int s = csr[j];
                float w = c_ta_s[s];
                float4 xv = *(const float4*)(x_t + (size_t)s * 32 + k4 * 4);
                accT.x = fmaf(xv.x, w, accT.x); accT.y = fmaf(xv.y, w, accT.y);
                accT.z = fmaf(xv.z, w, accT.z); accT.w = fmaf(xv.w, w, accT.w);
            }
            // self-loop
            accA.x = fmaf(xs.x, ci, accA.x); accA.y = fmaf(xs.y, ci, accA.y);
            accA.z = fmaf(xs.z, ci, accA.z); accA.w = fmaf(xs.w, ci, accA.w);

            // (3) issue: next group's csr preload (latency covered by matvec below)
            int nsA = -1, nsT = -1;
            if (more) {
                int nna = ne0 - nb0, nnt = ne1 - nb1;
                nsA = (lane < nna) ? (int)csr[nb0 + lane] : -1;
                nsT = (lane < nnt) ? (int)csr[nb1 + lane] : -1;
            }

            // (4) reduce across e8 groups + matvec
#pragma unroll
            for (int m = 8; m <= 32; m <<= 1) {
                accA.x += __shfl_xor(accA.x, m, 64);
                accA.y += __shfl_xor(accA.y, m, 64);
                accA.z += __shfl_xor(accA.z, m, 64);
                accA.w += __shfl_xor(accA.w, m, 64);
                accT.x += __shfl_xor(accT.x, m, 64);
                accT.y += __shfl_xor(accT.y, m, 64);
                accT.z += __shfl_xor(accT.z, m, 64);
                accT.w += __shfl_xor(accT.w, m, 64);
            }
            float hA = 0.f, hT = 0.f;
#pragma unroll
            for (int g2 = 0; g2 < 8; ++g2) {
                float a0 = bcast(accA.x, g2), a1 = bcast(accA.y, g2);
                float a2 = bcast(accA.z, g2), a3 = bcast(accA.w, g2);
                float t0 = bcast(accT.x, g2), t1 = bcast(accT.y, g2);
                float t2 = bcast(accT.z, g2), t3 = bcast(accT.w, g2);
                const float* wa = wbA + g2 * 4;
                const float* wt = wbT + g2 * 4;
                hA = fmaf(a0, wa[0], hA); hA = fmaf(a1, wa[1], hA);
                hA = fmaf(a2, wa[2], hA); hA = fmaf(a3, wa[3], hA);
                hT = fmaf(t0, wt[0], hT); hT = fmaf(t1, wt[1], hT);
                hT = fmaf(t2, wt[2], hT); hT = fmaf(t3, wt[3], hT);
            }

            // (5) issue: next group's edge-coef gathers (csr has landed by now)
            float ncA = 0.f, ncT = 0.f;
            if (more) {
                ncA = (nsA >= 0) ? c_aa[nsA] : 0.f;
                ncT = (nsT >= 0) ? c_ta_s[nsT] : 0.f;
            }

            // (6) finish current node: relu, fused projection, store
            float h = fmaxf(bias + ci * hA + ctd * hT, 0.f);
            float p0 = h * u0, p1 = h * u1;
            float q0 = h * u2, q1 = h * u3;
#pragma unroll
            for (int m = 32; m; m >>= 1) {
                p0 += __shfl_xor(p0, m, 64);
                p1 += __shfl_xor(p1, m, 64);
                q0 += __shfl_xor(q0, m, 64);
                q1 += __shfl_xor(q1, m, 64);
            }
            if (lane == 0) {
                *(float2*)&p[i * 2] = make_float2(p0 * ci, p1 * ci);
                *(float2*)&q[i * 2] = make_float2(q0 * cq, q1 * cq);
            }

            if (!more) break;
            // (7) rotate pipeline state
            g = gn; i = in_;
            b0 = nb0; e0v = ne0; b1 = nb1; e1v = ne1;
            na = ne0 - nb0; nt = ne1 - nb1;
            sA = nsA; sT = nsT; cAv = ncA; cTv = ncT;
        }
    } else {
        // ---------- targets: groups g = blockIdx.x-NAB, +NTB, ... < 6250 ----------
        for (int idx = threadIdx.x; idx < 2048; idx += 256) {
            int k = idx >> 6, col = idx & 63;
            sW0[col * 33 + k] = W_at[idx];
        }
        __syncthreads();
        float bias = b_at[lane];
        float u0 = U[128 + lane * 2], u1 = U[128 + lane * 2 + 1];
        const float* wbA = sW0 + lane * 33;

        int g = blockIdx.x - NAB;
        int i = g * 4 + wid;
        int b0 = ro[2 * NA + i], e0v = ro[2 * NA + i + 1];
        int na = e0v - b0;
        int sA = (lane < na) ? (int)csr[b0 + lane] : -1;
        float cAv = (sA >= 0) ? c_at_s[sA] : 0.f;

        while (true) {
            int gn = g + NTB;
            bool more = gn < 6250;
            int in_ = gn * 4 + wid;
            int nb0 = 0, ne0 = 0;
            if (more) { nb0 = ro[2 * NA + in_]; ne0 = ro[2 * NA + in_ + 1]; }
            float cd = c_at_d[i], cr = c_ta_s[i];

            float4 acc = make_float4(0.f, 0.f, 0.f, 0.f);
            int nG = (min(na, 64) + 7) >> 3;
            int ga = 0;
            for (; ga + 2 <= nG; ga += 2) {
                int s0 = __shfl(sA, ga * 8 + e8, 64);
                int s1 = __shfl(sA, ga * 8 + 8 + e8, 64);
                float w0 = __shfl(cAv, ga * 8 + e8, 64);
                float w1 = __shfl(cAv, ga * 8 + 8 + e8, 64);
                float4 x0 = make_float4(0.f, 0.f, 0.f, 0.f), x1 = x0;
                if (s0 >= 0) x0 = *(const float4*)(x_a + (size_t)s0 * 32 + k4 * 4);
                if (s1 >= 0) x1 = *(const float4*)(x_a + (size_t)s1 * 32 + k4 * 4);
                acc.x = fmaf(x0.x, w0, acc.x); acc.y = fmaf(x0.y, w0, acc.y);
                acc.z = fmaf(x0.z, w0, acc.z); acc.w = fmaf(x0.w, w0, acc.w);
                acc.x = fmaf(x1.x, w1, acc.x); acc.y = fmaf(x1.y, w1, acc.y);
                acc.z = fmaf(x1.z, w1, acc.z); acc.w = fmaf(x1.w, w1, acc.w);
            }
            if (ga < nG) {
                int s0 = __shfl(sA, ga * 8 + e8, 64);
                float w0 = __shfl(cAv, ga * 8 + e8, 64);
                float4 x0 = make_float4(0.f, 0.f, 0.f, 0.f);
                if (s0 >= 0) x0 = *(const float4*)(x_a + (size_t)s0 * 32 + k4 * 4);
                acc.x = fmaf(x0.x, w0, acc.x); acc.y = fmaf(x0.y, w0, acc.y);
                acc.z = fmaf(x0.z, w0, acc.z); acc.w = fmaf(x0.w, w0, acc.w);
            }
            for (int j = b0 + 64 + e8; j < e0v; j += 8) {   // rare tail
                int s = csr[j];
                float w = c_at_s[s];
                float4 xv = *(const float4*)(x_a + (size_t)s * 32 + k4 * 4);
                acc.x = fmaf(xv.x, w, acc.x); acc.y = fmaf(xv.y, w, acc.y);
                acc.z = fmaf(xv.z, w, acc.z); acc.w = fmaf(xv.w, w, acc.w);
            }

            int nsA = -1;
            if (more) {
                int nna = ne0 - nb0;
                nsA = (lane < nna) ? (int)csr[nb0 + lane] : -1;
            }

#pragma unroll
            for (int m = 8; m <= 32; m <<= 1) {
                acc.x += __shfl_xor(acc.x, m, 64);
                acc.y += __shfl_xor(acc.y, m, 64);
                acc.z += __shfl_xor(acc.z, m, 64);
                acc.w += __shfl_xor(acc.w, m, 64);
            }
            float hA = 0.f;
#pragma unroll
            for (int g2 = 0; g2 < 8; ++g2) {
                float a0 = bcast(acc.x, g2), a1 = bcast(acc.y, g2);
                float a2 = bcast(acc.z, g2), a3 = bcast(acc.w, g2);
                const float* wa = wbA + g2 * 4;
                hA = fmaf(a0, wa[0], hA); hA = fmaf(a1, wa[1], hA);
                hA = fmaf(a2, wa[2], hA); hA = fmaf(a3, wa[3], hA);
            }

            float ncA = 0.f;
            if (more) ncA = (nsA >= 0) ? c_at_s[nsA] : 0.f;

            float h = fmaxf(bias + cd * hA, 0.f);
            float r0 = h * u0, r1 = h * u1;
#pragma unroll
            for (int m = 32; m; m >>= 1) {
                r0 += __shfl_xor(r0, m, 64);
                r1 += __shfl_xor(r1, m, 64);
            }
            if (lane == 0) {
                *(float2*)&r[i * 2] = make_float2(r0 * cr, r1 * cr);
            }

            if (!more) break;
            g = gn; i = in_;
            b0 = nb0; e0v = ne0; na = ne0 - nb0;
            sA = nsA; cAv = ncA;
        }
    }
}

// ---------- conv2+proj: one wave per node, 32 edge slots x 2 comps ----------
__global__ void __launch_bounds__(256)
out_all_kernel(const float* __restrict__ p, const float* __restrict__ q,
               const float* __restrict__ r, const int* __restrict__ ro,
               const unsigned short* __restrict__ csr,
               const float* __restrict__ c_aa, const float* __restrict__ c_ta_d,
               const float* __restrict__ c_at_d, const float* __restrict__ U,
               float* __restrict__ out) {
    int wgid = blockIdx.x * 4 + (threadIdx.x >> 6);
    int lane = threadIdx.x & 63;
    int slot = lane >> 1, j = lane & 1;
    if (wgid < NA) {
        int i = wgid;
        int b0 = ro[i], n0 = ro[i + 1] - b0;
        float accA = (slot == 0) ? p[i * 2 + j] : 0.f;   // self-loop (p premultiplied)
        for (int e = slot; e < n0; e += 32) accA += p[(int)csr[b0 + e] * 2 + j];
        int b1 = ro[NA + i], n1 = ro[NA + i + 1] - b1;
        float accT = 0.f;
        for (int e = slot; e < n1; e += 32) accT += r[(int)csr[b1 + e] * 2 + j];
#pragma unroll
        for (int m = 2; m <= 32; m <<= 1) {
            accA += __shfl_xor(accA, m, 64);
            accT += __shfl_xor(accT, m, 64);
        }
        if (lane < 2) out[i * 2 + j] = U[384 + j] + accA * c_aa[i] + accT * c_ta_d[i];
    } else {
        int i = wgid - NA;
        int b0 = ro[2 * NA + i], n0 = ro[2 * NA + i + 1] - b0;
        float acc = 0.f;
        for (int e = slot; e < n0; e += 32) acc += q[(int)csr[b0 + e] * 2 + j];
#pragma unroll
        for (int m = 2; m <= 32; m <<= 1) acc += __shfl_xor(acc, m, 64);
        if (lane < 2) out[NA * 2 + i * 2 + j] = U[386 + j] + acc * c_at_d[i];
    }
}

extern "C" void kernel_launch(void* const* d_in, const int* in_sizes, int n_in,
                              void* d_out, int out_size, void* d_ws, size_t ws_size,
                              hipStream_t stream) {
    const float* x_a   = (const float*)d_in[1];
    const float* x_t   = (const float*)d_in[2];
    const int* src_aa  = (const int*)d_in[3];
    const int* dst_aa  = (const int*)d_in[4];
    const int* src_at  = (const int*)d_in[5];
    const int* dst_at  = (const int*)d_in[6];
    const int* src_ta  = (const int*)d_in[7];
    const int* dst_ta  = (const int*)d_in[8];
    const float* W1_aa = (const float*)d_in[9];
    const float* b1_aa = (const float*)d_in[10];
    const float* W1_at = (const float*)d_in[11];
    const float* b1_at = (const float*)d_in[12];
    const float* W1_ta = (const float*)d_in[13];
    const float* b1_ta = (const float*)d_in[14];
    const float* W2_aa = (const float*)d_in[15];
    const float* b2_aa = (const float*)d_in[16];
    const float* W2_at = (const float*)d_in[17];
    const float* b2_at = (const float*)d_in[18];
    const float* W2_ta = (const float*)d_in[19];
    const float* b2_ta = (const float*)d_in[20];
    const float* Wp_a  = (const float*)d_in[21];
    const float* bp_a  = (const float*)d_in[22];
    const float* Wp_t  = (const float*)d_in[23];
    const float* bp_t  = (const float*)d_in[24];

    int*   wi  = (int*)d_ws;
    float* wf  = (float*)d_ws;
    unsigned short* csr = (unsigned short*)(wi + O_CSR);
    float* out = (float*)d_out;

    // single memset: 8-copy src-degree histograms + adjacent bucket totals
    hipMemsetAsync(wi + O_SRCH, 0, (size_t)(8 * SRCH_STRIDE + 512) * 4, stream);

    // fused pass 1: single edge read -> LDS bucket sort -> slab flush (+ src degrees)
    p1_fused_kernel<<<NBLK1, 1024, 0, stream>>>(src_aa, dst_aa, src_ta, dst_ta,
                                                src_at, dst_at, wi);

    // fused pass 2 + aux: p2 (self-computed bases) | src coefs | U fuse
    p2_aux_kernel<<<NB + 75, 1024, 0, stream>>>(wi, wf, W2_aa, W2_ta, W2_at,
                                                b2_aa, b2_ta, b2_at,
                                                Wp_a, bp_a, Wp_t, bp_t);

    // conv1: persistent blocks, pipelined groups
    conv1_all_kernel<<<NAB + NTB, 256, 0, stream>>>(
        x_a, x_t, wi + O_RO, csr,
        wf + O_CAA, wf + O_CTAD, wf + O_CTAS, wf + O_CATS, wf + O_CATD,
        W1_aa, b1_aa, W1_ta, b1_ta, W1_at, b1_at, wf + O_U,
        wf + O_P, wf + O_Q, wf + O_R);

    // conv2 + projection, wave per node
    out_all_kernel<<<(NA + NT) / 4, 256, 0, stream>>>(
        wf + O_P, wf + O_Q, wf + O_R, wi + O_RO, csr,
        wf + O_CAA, wf + O_CTAD, wf + O_CATD, wf + O_U, out);
}

// Round 3
// 246.373 us; speedup vs baseline: 1.6450x; 1.0055x over previous
//
#include <hip/hip_runtime.h>

#define NA 50000
#define NT 25000
#define EAA 800000
#define EAT 400000
#define ETA 400000
#define NSEG 125000          // NA + NA + NT rows: [aa | ta | at]
#define TOTAL_E 1600000
#define NB 489               // coarse buckets of 256 rows
#define NBLK1 391            // pass-1 blocks
#define CHUNK 4096           // edges per pass-1 block
#define CAP 6144             // REC slab capacity per bucket (max observed bucket ~4800)
#define SRCH_STRIDE 75008    // per-copy src-histogram stride: at[50000] | ta[25000] | pad

// conv1 persistent grid: 512 blocks x 1024 threads = 2 blocks/CU = 32 waves/CU (forced full occupancy)
#define C1_AB 390            // agent blocks (16 waves each -> 6240 agent wave-streams)
#define C1_TB 122            // target blocks (1952 target wave-streams)
#define C1_AS (C1_AB * 16)   // agent node stride
#define C1_TS (C1_TB * 16)   // target node stride

// ---- workspace layout (4-byte element offsets) ----
#define O_SRCH    0          // int[8*75008]: 8 XCD-local src-degree histogram copies
#define O_BTOT    600064     // int[512]: per-bucket totals (adjacent to SRCH -> single memset)
#define O_RO      600576     // int[125001]: CSR row offsets
#define O_CAA     725584     // float[50000]: rsqrt(indeg_aa+1)
#define O_CTAD    775584     // float[50000]
#define O_CATD    825584     // float[25000]
#define O_CATS    850584     // float[50000]
#define O_CTAS    900584     // float[25000]
#define O_U       925600     // float[512] (padded start)
#define O_P       926112     // float[100000]
#define O_Q       1026112    // float[100000]
#define O_R       1126112    // float[50000]
#define O_REC     1176112    // int[NB*CAP=3004416]: slabbed bucket-sorted records
#define O_CSR     4180528    // ushort[1600000] = 800000 ints

__device__ __forceinline__ float bcast(float v, int l) {
    return __int_as_float(__builtin_amdgcn_readlane(__float_as_int(v), l));
}

// ---------- fused pass 1: load edges once -> LDS bucket sort -> slab flush (+ src degrees) ----------
__global__ void __launch_bounds__(1024)
p1_fused_kernel(const int* __restrict__ src_aa, const int* __restrict__ dst_aa,
                const int* __restrict__ src_ta, const int* __restrict__ dst_ta,
                const int* __restrict__ src_at, const int* __restrict__ dst_at,
                int* __restrict__ wi) {
    __shared__ int recs[CHUNK];              // staged packed (rl<<16)|src
    __shared__ unsigned short bkt[CHUNK];    // bucket per staged edge
    __shared__ int sorted[CHUNK];            // bucket-sorted records
    __shared__ unsigned short sbkt[CHUNK];   // bucket per sorted slot
    __shared__ int cnt[NB];                  // per-bucket count
    __shared__ int cur[NB];                  // scan cursor (ends at offs+cnt)
    __shared__ int gbase[NB];                // scan buffer, then global base - offs
    int b = blockIdx.x, tid = threadIdx.x;
    int* rec_g = wi + O_REC;

    for (int i = tid; i < NB; i += 1024) cnt[i] = 0;
    __syncthreads();

    // phase A: load + stage + count (+ XCD-local src-degree atomics)
    int t0 = b * CHUNK;
    int n = min(CHUNK, TOTAL_E - t0);
    int* srch = wi + O_SRCH + (b & 7) * SRCH_STRIDE;
    for (int i = tid; i < n; i += 1024) {
        int t = t0 + i, row, s;
        if (t < EAA) {
            row = dst_aa[t]; s = src_aa[t];
        } else if (t < EAA + ETA) {
            int u = t - EAA;
            row = NA + dst_ta[u]; s = src_ta[u];
            atomicAdd(&srch[50000 + s], 1);
        } else {
            int u = t - EAA - ETA;
            row = 2 * NA + dst_at[u]; s = src_at[u];
            atomicAdd(&srch[s], 1);
        }
        int bk = row >> 8;
        recs[i] = ((row & 255) << 16) | s;
        bkt[i] = (unsigned short)bk;
        atomicAdd(&cnt[bk], 1);
    }
    __syncthreads();

    // phase B: exclusive scan of cnt -> cur (scan buffer = gbase)
    if (tid < NB) gbase[tid] = cnt[tid];
    __syncthreads();
    for (int off = 1; off < NB; off <<= 1) {
        int x = 0;
        if (tid < NB && tid >= off) x = gbase[tid - off];
        __syncthreads();
        if (tid < NB) gbase[tid] += x;
        __syncthreads();
    }
    if (tid < NB) cur[tid] = gbase[tid] - cnt[tid];   // exclusive offs
    __syncthreads();

    // phase C: place into LDS-sorted order
    for (int i = tid; i < n; i += 1024) {
        int bk = bkt[i];
        int pos = atomicAdd(&cur[bk], 1);
        sorted[pos] = recs[i];
        sbkt[pos] = (unsigned short)bk;
    }
    __syncthreads();

    // phase D: reserve global slab space per bucket; gbase = slab_base - offs
    for (int bk = tid; bk < NB; bk += 1024) {
        int len = cnt[bk];
        if (len > 0) {
            int gb = atomicAdd(&wi[O_BTOT + bk], len);
            gbase[bk] = bk * CAP + gb - (cur[bk] - len);   // cur now = offs+len
        }
    }
    __syncthreads();

    // phase E: flush contiguous runs to the slab
    for (int i = tid; i < n; i += 1024) {
        int bk = sbkt[i];
        rec_g[gbase[bk] + i] = sorted[i];
    }
}

// ---------- fused pass 2 + aux: blocks 0..NB-1 = p2 (self-computed base); NB..NB+73 = src coefs; NB+74 = U ----------
__global__ void __launch_bounds__(1024)
p2_aux_kernel(int* __restrict__ wi, float* __restrict__ wf,
              const float* __restrict__ W2_aa, const float* __restrict__ W2_ta,
              const float* __restrict__ W2_at, const float* __restrict__ b2_aa,
              const float* __restrict__ b2_ta, const float* __restrict__ b2_at,
              const float* __restrict__ Wp_a, const float* __restrict__ bp_a,
              const float* __restrict__ Wp_t, const float* __restrict__ bp_t) {
    int bb = blockIdx.x, tid = threadIdx.x, lane = tid & 63, wid = tid >> 6;
    if (bb < NB) {
        const int* rec = wi + O_REC;
        unsigned short* csr = (unsigned short*)(wi + O_CSR);
        int* ro = wi + O_RO;
        float* caa = wf + O_CAA;
        float* ctad = wf + O_CTAD;
        float* catd = wf + O_CATD;
        __shared__ int deg[256];
        __shared__ int rb[256];
        __shared__ int wsum[16];
        int k = bb;
        // self-compute g0 = sum of BTOT[0..k)
        int a = (tid < k) ? wi[O_BTOT + tid] : 0;
#pragma unroll
        for (int m = 32; m; m >>= 1) a += __shfl_xor(a, m, 64);
        if (lane == 0) wsum[wid] = a;
        if (tid < 256) deg[tid] = 0;
        __syncthreads();
        int g0 = 0;
#pragma unroll
        for (int w = 0; w < 16; ++w) g0 += wsum[w];
        int s0 = k * CAP;                       // slab base
        int len = wi[O_BTOT + k];
        for (int j = tid; j < len; j += 1024) atomicAdd(&deg[rec[s0 + j] >> 16], 1);
        __syncthreads();
        int v = 0, x = 0;
        if (tid < 256) {
            v = deg[tid];
            x = v;
#pragma unroll
            for (int off = 1; off < 64; off <<= 1) {
                int y = __shfl_up(x, off, 64);
                if (lane >= off) x += y;
            }
            if (lane == 63) wsum[wid] = x;
        }
        __syncthreads();
        if (tid < 256) {
            int wpre = 0;
            for (int w = 0; w < wid; ++w) wpre += wsum[w];
            int excl = x - v + wpre;
            rb[tid] = g0 + excl;
            int g = k * 256 + tid;
            if (g < NSEG) {
                ro[g] = g0 + excl;
                if (g < NA) caa[g] = rsqrtf((float)v + 1.0f);
                else if (g < 2 * NA) ctad[g - NA] = v > 0 ? rsqrtf((float)v) : 0.0f;
                else catd[g - 2 * NA] = v > 0 ? rsqrtf((float)v) : 0.0f;
            }
            if (k == NB - 1 && tid == 0) ro[NSEG] = TOTAL_E;
        }
        __syncthreads();
        for (int j = tid; j < len; j += 1024) {
            int rc = rec[s0 + j];
            int pos = atomicAdd(&rb[rc >> 16], 1);
            csr[pos] = (unsigned short)(rc & 0xFFFF);
        }
    } else if (bb < NB + 74) {
        int t = (bb - NB) * 1024 + tid;
        if (t < 75000) {
            int d = 0;
#pragma unroll
            for (int c = 0; c < 8; ++c) d += wi[O_SRCH + c * SRCH_STRIDE + t];
            float v = d > 0 ? rsqrtf((float)d) : 0.0f;
            if (t < 50000) wf[O_CATS + t] = v;
            else           wf[O_CTAS + (t - 50000)] = v;
        }
    } else {
        float* U = wf + O_U;
        int t = tid;
        if (t < 128) {
            int k = t >> 1, j = t & 1;
            float a = 0.f;
            for (int f = 0; f < 64; ++f) a = fmaf(W2_aa[k * 64 + f], Wp_a[f * 2 + j], a);
            U[t] = a;
        } else if (t < 256) {
            int u = t - 128; int k = u >> 1, j = u & 1;
            float a = 0.f;
            for (int f = 0; f < 64; ++f) a = fmaf(W2_ta[k * 64 + f], Wp_a[f * 2 + j], a);
            U[128 + u] = a;
        } else if (t < 384) {
            int u = t - 256; int k = u >> 1, j = u & 1;
            float a = 0.f;
            for (int f = 0; f < 64; ++f) a = fmaf(W2_at[k * 64 + f], Wp_t[f * 2 + j], a);
            U[256 + u] = a;
        } else if (t < 386) {
            int j = t - 384;
            float a = bp_a[j];
            for (int f = 0; f < 64; ++f) a = fmaf(b2_aa[f] + b2_ta[f], Wp_a[f * 2 + j], a);
            U[384 + j] = a;
        } else if (t < 388) {
            int j = t - 386;
            float a = bp_t[j];
            for (int f = 0; f < 64; ++f) a = fmaf(b2_at[f], Wp_t[f * 2 + j], a);
            U[386 + j] = a;
        }
    }
}

// ---------- conv1: 512 x 1024-thread persistent blocks (2 blocks/CU = 32 waves/CU forced),
//            per-wave node streams, 1-deep pipeline, unroll-2 gather, coef-via-shfl.
//            W in LDS: transposed, stride 33 (2-way bank alias = free; 0 conflicts measured).
//            R2 showed 256-thread blocks only achieved ~37% occupancy -> residency-limited. ----------
__global__ void __launch_bounds__(1024, 4)
conv1_all_kernel(const float* __restrict__ x_a, const float* __restrict__ x_t,
                 const int* __restrict__ ro, const unsigned short* __restrict__ csr,
                 const float* __restrict__ c_aa, const float* __restrict__ c_ta_d,
                 const float* __restrict__ c_ta_s, const float* __restrict__ c_at_s,
                 const float* __restrict__ c_at_d,
                 const float* __restrict__ W_aa, const float* __restrict__ b_aa,
                 const float* __restrict__ W_ta, const float* __restrict__ b_ta,
                 const float* __restrict__ W_at, const float* __restrict__ b_at,
                 const float* __restrict__ U,
                 float* __restrict__ p, float* __restrict__ q, float* __restrict__ r) {
    __shared__ float sW0[64 * 33];   // sW[col*33 + k] = W[k][col]
    __shared__ float sW1[64 * 33];
    int lane = threadIdx.x & 63;
    int wid = threadIdx.x >> 6;      // 0..15
    int e8 = lane >> 3, k4 = lane & 7;

    if (blockIdx.x < C1_AB) {
        // ---------- agents: wave-stream i = wv, wv+C1_AS, ... < NA ----------
        for (int idx = threadIdx.x; idx < 2048; idx += 1024) {
            int k = idx >> 6, col = idx & 63;
            sW0[col * 33 + k] = W_aa[idx];
            sW1[col * 33 + k] = W_ta[idx];
        }
        __syncthreads();
        float bias = b_aa[lane] + b_ta[lane];
        float u0 = U[lane * 2], u1 = U[lane * 2 + 1];
        float u2 = U[256 + lane * 2], u3 = U[256 + lane * 2 + 1];
        const float* wbA = sW0 + lane * 33;
        const float* wbT = sW1 + lane * 33;

        int i = blockIdx.x * 16 + wid;   // 0..6239 < NA, always valid
        // prologue: current node's rows + csr + edge-coefs
        int b0 = ro[i], e0v = ro[i + 1];
        int b1 = ro[NA + i], e1v = ro[NA + i + 1];
        int na = e0v - b0, nt = e1v - b1;
        int sA = (lane < na) ? (int)csr[b0 + lane] : -1;
        int sT = (lane < nt) ? (int)csr[b1 + lane] : -1;
        float cAv = (sA >= 0) ? c_aa[sA] : 0.f;
        float cTv = (sT >= 0) ? c_ta_s[sT] : 0.f;

        while (true) {
            // (1) issue: next node's row offsets + current node coefs + self-loop row
            int ni = i + C1_AS;
            bool more = ni < NA;
            int nb0 = 0, ne0 = 0, nb1 = 0, ne1 = 0;
            if (more) {
                nb0 = ro[ni]; ne0 = ro[ni + 1];
                nb1 = ro[NA + ni]; ne1 = ro[NA + ni + 1];
            }
            float ci = c_aa[i], ctd = c_ta_d[i], cq = c_at_s[i];
            float4 xs = make_float4(0.f, 0.f, 0.f, 0.f);
            if (e8 == 0) xs = *(const float4*)(x_a + (size_t)i * 32 + k4 * 4);

            // (2) gathers for current node (unroll-2: two x rows in flight)
            float4 accA = make_float4(0.f, 0.f, 0.f, 0.f);
            float4 accT = make_float4(0.f, 0.f, 0.f, 0.f);
            int nGA = (min(na, 64) + 7) >> 3;
            int nGT = (min(nt, 64) + 7) >> 3;
            int ga = 0;
            for (; ga + 2 <= nGA; ga += 2) {
                int s0 = __shfl(sA, ga * 8 + e8, 64);
                int s1 = __shfl(sA, ga * 8 + 8 + e8, 64);
                float w0 = __shfl(cAv, ga * 8 + e8, 64);
                float w1 = __shfl(cAv, ga * 8 + 8 + e8, 64);
                float4 x0 = make_float4(0.f, 0.f, 0.f, 0.f), x1 = x0;
                if (s0 >= 0) x0 = *(const float4*)(x_a + (size_t)s0 * 32 + k4 * 4);
                if (s1 >= 0) x1 = *(const float4*)(x_a + (size_t)s1 * 32 + k4 * 4);
                accA.x = fmaf(x0.x, w0, accA.x); accA.y = fmaf(x0.y, w0, accA.y);
                accA.z = fmaf(x0.z, w0, accA.z); accA.w = fmaf(x0.w, w0, accA.w);
                accA.x = fmaf(x1.x, w1, accA.x); accA.y = fmaf(x1.y, w1, accA.y);
                accA.z = fmaf(x1.z, w1, accA.z); accA.w = fmaf(x1.w, w1, accA.w);
            }
            if (ga < nGA) {
                int s0 = __shfl(sA, ga * 8 + e8, 64);
                float w0 = __shfl(cAv, ga * 8 + e8, 64);
                float4 x0 = make_float4(0.f, 0.f, 0.f, 0.f);
                if (s0 >= 0) x0 = *(const float4*)(x_a + (size_t)s0 * 32 + k4 * 4);
                accA.x = fmaf(x0.x, w0, accA.x); accA.y = fmaf(x0.y, w0, accA.y);
                accA.z = fmaf(x0.z, w0, accA.z); accA.w = fmaf(x0.w, w0, accA.w);
            }
            for (int j = b0 + 64 + e8; j < e0v; j += 8) {   // rare tail
                int s = csr[j];
                float w = c_aa[s];
                float4 xv = *(const float4*)(x_a + (size_t)s * 32 + k4 * 4);
                accA.x = fmaf(xv.x, w, accA.x); accA.y = fmaf(xv.y, w, accA.y);
                accA.z = fmaf(xv.z, w, accA.z); accA.w = fmaf(xv.w, w, accA.w);
            }
            int gt = 0;
            for (; gt + 2 <= nGT; gt += 2) {
                int s0 = __shfl(sT, gt * 8 + e8, 64);
                int s1 = __shfl(sT, gt * 8 + 8 + e8, 64);
                float w0 = __shfl(cTv, gt * 8 + e8, 64);
                float w1 = __shfl(cTv, gt * 8 + 8 + e8, 64);
                float4 x0 = make_float4(0.f, 0.f, 0.f, 0.f), x1 = x0;
                if (s0 >= 0) x0 = *(const float4*)(x_t + (size_t)s0 * 32 + k4 * 4);
                if (s1 >= 0) x1 = *(const float4*)(x_t + (size_t)s1 * 32 + k4 * 4);
                accT.x = fmaf(x0.x, w0, accT.x); accT.y = fmaf(x0.y, w0, accT.y);
                accT.z = fmaf(x0.z, w0, accT.z); accT.w = fmaf(x0.w, w0, accT.w);
                accT.x = fmaf(x1.x, w1, accT.x); accT.y = fmaf(x1.y, w1, accT.y);
                accT.z = fmaf(x1.z, w1, accT.z); accT.w = fmaf(x1.w, w1, accT.w);
            }
            if (gt < nGT) {
                int s0 = __shfl(sT, gt * 8 + e8, 64);
                float w0 = __shfl(cTv, gt * 8 + e8, 64);
                float4 x0 = make_float4(0.f, 0.f, 0.f, 0.f);
                if (s0 >= 0) x0 = *(const float4*)(x_t + (size_t)s0 * 32 + k4 * 4);
                accT.x = fmaf(x0.x, w0, accT.x); accT.y = fmaf(x0.y, w0, accT.y);
                accT.z = fmaf(x0.z, w0, accT.z); accT.w = fmaf(x0.w, w0, accT.w);
            }
            for (int j = b1 + 64 + e8; j < e1v; j += 8) {   // rare tail
                int s = csr[j];
                float w = c_ta_s[s];
                float4 xv = *(const float4*)(x_t + (size_t)s * 32 + k4 * 4);
                accT.x = fmaf(xv.x, w, accT.x); accT.y = fmaf(xv.y, w, accT.y);
                accT.z = fmaf(xv.z, w, accT.z); accT.w = fmaf(xv.w, w, accT.w);
            }
            // self-loop
            accA.x = fmaf(xs.x, ci, accA.x); accA.y = fmaf(xs.y, ci, accA.y);
            accA.z = fmaf(xs.z, ci, accA.z); accA.w = fmaf(xs.w, ci, accA.w);

            // (3) issue: next node's csr preload (latency covered by matvec below)
            int nsA = -1, nsT = -1;
            if (more) {
                int nna = ne0 - nb0, nnt = ne1 - nb1;
                nsA = (lane < nna) ? (int)csr[nb0 + lane] : -1;
                nsT = (lane < nnt) ? (int)csr[nb1 + lane] : -1;
            }

            // (4) reduce across e8 groups + matvec
#pragma unroll
            for (int m = 8; m <= 32; m <<= 1) {
                accA.x += __shfl_xor(accA.x, m, 64);
                accA.y += __shfl_xor(accA.y, m, 64);
                accA.z += __shfl_xor(accA.z, m, 64);
                accA.w += __shfl_xor(accA.w, m, 64);
                accT.x += __shfl_xor(accT.x, m, 64);
                accT.y += __shfl_xor(accT.y, m, 64);
                accT.z += __shfl_xor(accT.z, m, 64);
                accT.w += __shfl_xor(accT.w, m, 64);
            }
            float hA = 0.f, hT = 0.f;
#pragma unroll
            for (int g2 = 0; g2 < 8; ++g2) {
                float a0 = bcast(accA.x, g2), a1 = bcast(accA.y, g2);
                float a2 = bcast(accA.z, g2), a3 = bcast(accA.w, g2);
                float t0 = bcast(accT.x, g2), t1 = bcast(accT.y, g2);
                float t2 = bcast(accT.z, g2), t3 = bcast(accT.w, g2);
                const float* wa = wbA + g2 * 4;
                const float* wt = wbT + g2 * 4;
                hA = fmaf(a0, wa[0], hA); hA = fmaf(a1, wa[1], hA);
                hA = fmaf(a2, wa[2], hA); hA = fmaf(a3, wa[3], hA);
                hT = fmaf(t0, wt[0], hT); hT = fmaf(t1, wt[1], hT);
                hT = fmaf(t2, wt[2], hT); hT = fmaf(t3, wt[3], hT);
            }

            // (5) issue: next node's edge-coef gathers (csr has landed by now)
            float ncA = 0.f, ncT = 0.f;
            if (more) {
                ncA = (nsA >= 0) ? c_aa[nsA] : 0.f;
                ncT = (nsT >= 0) ? c_ta_s[nsT] : 0.f;
            }

            // (6) finish current node: relu, fused projection, store
            float h = fmaxf(bias + ci * hA + ctd * hT, 0.f);
            float p0 = h * u0, p1 = h * u1;
            float q0 = h * u2, q1 = h * u3;
#pragma unroll
            for (int m = 32; m; m >>= 1) {
                p0 += __shfl_xor(p0, m, 64);
                p1 += __shfl_xor(p1, m, 64);
                q0 += __shfl_xor(q0, m, 64);
                q1 += __shfl_xor(q1, m, 64);
            }
            if (lane == 0) {
                *(float2*)&p[i * 2] = make_float2(p0 * ci, p1 * ci);
                *(float2*)&q[i * 2] = make_float2(q0 * cq, q1 * cq);
            }

            if (!more) break;
            // (7) rotate pipeline state
            i = ni;
            b0 = nb0; e0v = ne0; b1 = nb1; e1v = ne1;
            na = ne0 - nb0; nt = ne1 - nb1;
            sA = nsA; sT = nsT; cAv = ncA; cTv = ncT;
        }
    } else {
        // ---------- targets: wave-stream i = wv, wv+C1_TS, ... < NT ----------
        for (int idx = threadIdx.x; idx < 2048; idx += 1024) {
            int k = idx >> 6, col = idx & 63;
            sW0[col * 33 + k] = W_at[idx];
        }
        __syncthreads();
        float bias = b_at[lane];
        float u0 = U[128 + lane * 2], u1 = U[128 + lane * 2 + 1];
        const float* wbA = sW0 + lane * 33;

        int i = (blockIdx.x - C1_AB) * 16 + wid;   // 0..1951 < NT, always valid
        int b0 = ro[2 * NA + i], e0v = ro[2 * NA + i + 1];
        int na = e0v - b0;
        int sA = (lane < na) ? (int)csr[b0 + lane] : -1;
        float cAv = (sA >= 0) ? c_at_s[sA] : 0.f;

        while (true) {
            int ni = i + C1_TS;
            bool more = ni < NT;
            int nb0 = 0, ne0 = 0;
            if (more) { nb0 = ro[2 * NA + ni]; ne0 = ro[2 * NA + ni + 1]; }
            float cd = c_at_d[i], cr = c_ta_s[i];

            float4 acc = make_float4(0.f, 0.f, 0.f, 0.f);
            int nG = (min(na, 64) + 7) >> 3;
            int ga = 0;
            for (; ga + 2 <= nG; ga += 2) {
                int s0 = __shfl(sA, ga * 8 + e8, 64);
                int s1 = __shfl(sA, ga * 8 + 8 + e8, 64);
                float w0 = __shfl(cAv, ga * 8 + e8, 64);
                float w1 = __shfl(cAv, ga * 8 + 8 + e8, 64);
                float4 x0 = make_float4(0.f, 0.f, 0.f, 0.f), x1 = x0;
                if (s0 >= 0) x0 = *(const float4*)(x_a + (size_t)s0 * 32 + k4 * 4);
                if (s1 >= 0) x1 = *(const float4*)(x_a + (size_t)s1 * 32 + k4 * 4);
                acc.x = fmaf(x0.x, w0, acc.x); acc.y = fmaf(x0.y, w0, acc.y);
                acc.z = fmaf(x0.z, w0, acc.z); acc.w = fmaf(x0.w, w0, acc.w);
                acc.x = fmaf(x1.x, w1, acc.x); acc.y = fmaf(x1.y, w1, acc.y);
                acc.z = fmaf(x1.z, w1, acc.z); acc.w = fmaf(x1.w, w1, acc.w);
            }
            if (ga < nG) {
                int s0 = __shfl(sA, ga * 8 + e8, 64);
                float w0 = __shfl(cAv, ga * 8 + e8, 64);
                float4 x0 = make_float4(0.f, 0.f, 0.f, 0.f);
                if (s0 >= 0) x0 = *(const float4*)(x_a + (size_t)s0 * 32 + k4 * 4);
                acc.x = fmaf(x0.x, w0, acc.x); acc.y = fmaf(x0.y, w0, acc.y);
                acc.z = fmaf(x0.z, w0, acc.z); acc.w = fmaf(x0.w, w0, acc.w);
            }
            for (int j = b0 + 64 + e8; j < e0v; j += 8) {   // rare tail
                int s = csr[j];
                float w = c_at_s[s];
                float4 xv = *(const float4*)(x_a + (size_t)s * 32 + k4 * 4);
                acc.x = fmaf(xv.x, w, acc.x); acc.y = fmaf(xv.y, w, acc.y);
                acc.z = fmaf(xv.z, w, acc.z); acc.w = fmaf(xv.w, w, acc.w);
            }

            int nsA = -1;
            if (more) {
                int nna = ne0 - nb0;
                nsA = (lane < nna) ? (int)csr[nb0 + lane] : -1;
            }

#pragma unroll
            for (int m = 8; m <= 32; m <<= 1) {
                acc.x += __shfl_xor(acc.x, m, 64);
                acc.y += __shfl_xor(acc.y, m, 64);
                acc.z += __shfl_xor(acc.z, m, 64);
                acc.w += __shfl_xor(acc.w, m, 64);
            }
            float hA = 0.f;
#pragma unroll
            for (int g2 = 0; g2 < 8; ++g2) {
                float a0 = bcast(acc.x, g2), a1 = bcast(acc.y, g2);
                float a2 = bcast(acc.z, g2), a3 = bcast(acc.w, g2);
                const float* wa = wbA + g2 * 4;
                hA = fmaf(a0, wa[0], hA); hA = fmaf(a1, wa[1], hA);
                hA = fmaf(a2, wa[2], hA); hA = fmaf(a3, wa[3], hA);
            }

            float ncA = 0.f;
            if (more) ncA = (nsA >= 0) ? c_at_s[nsA] : 0.f;

            float h = fmaxf(bias + cd * hA, 0.f);
            float r0 = h * u0, r1 = h * u1;
#pragma unroll
            for (int m = 32; m; m >>= 1) {
                r0 += __shfl_xor(r0, m, 64);
                r1 += __shfl_xor(r1, m, 64);
            }
            if (lane == 0) {
                *(float2*)&r[i * 2] = make_float2(r0 * cr, r1 * cr);
            }

            if (!more) break;
            i = ni;
            b0 = nb0; e0v = ne0; na = ne0 - nb0;
            sA = nsA; cAv = ncA;
        }
    }
}

// ---------- conv2+proj: one wave per node, 32 edge slots x 2 comps ----------
__global__ void __launch_bounds__(256)
out_all_kernel(const float* __restrict__ p, const float* __restrict__ q,
               const float* __restrict__ r, const int* __restrict__ ro,
               const unsigned short* __restrict__ csr,
               const float* __restrict__ c_aa, const float* __restrict__ c_ta_d,
               const float* __restrict__ c_at_d, const float* __restrict__ U,
               float* __restrict__ out) {
    int wgid = blockIdx.x * 4 + (threadIdx.x >> 6);
    int lane = threadIdx.x & 63;
    int slot = lane >> 1, j = lane & 1;
    if (wgid < NA) {
        int i = wgid;
        int b0 = ro[i], n0 = ro[i + 1] - b0;
        float accA = (slot == 0) ? p[i * 2 + j] : 0.f;   // self-loop (p premultiplied)
        for (int e = slot; e < n0; e += 32) accA += p[(int)csr[b0 + e] * 2 + j];
        int b1 = ro[NA + i], n1 = ro[NA + i + 1] - b1;
        float accT = 0.f;
        for (int e = slot; e < n1; e += 32) accT += r[(int)csr[b1 + e] * 2 + j];
#pragma unroll
        for (int m = 2; m <= 32; m <<= 1) {
            accA += __shfl_xor(accA, m, 64);
            accT += __shfl_xor(accT, m, 64);
        }
        if (lane < 2) out[i * 2 + j] = U[384 + j] + accA * c_aa[i] + accT * c_ta_d[i];
    } else {
        int i = wgid - NA;
        int b0 = ro[2 * NA + i], n0 = ro[2 * NA + i + 1] - b0;
        float acc = 0.f;
        for (int e = slot; e < n0; e += 32) acc += q[(int)csr[b0 + e] * 2 + j];
#pragma unroll
        for (int m = 2; m <= 32; m <<= 1) acc += __shfl_xor(acc, m, 64);
        if (lane < 2) out[NA * 2 + i * 2 + j] = U[386 + j] + acc * c_at_d[i];
    }
}

extern "C" void kernel_launch(void* const* d_in, const int* in_sizes, int n_in,
                              void* d_out, int out_size, void* d_ws, size_t ws_size,
                              hipStream_t stream) {
    const float* x_a   = (const float*)d_in[1];
    const float* x_t   = (const float*)d_in[2];
    const int* src_aa  = (const int*)d_in[3];
    const int* dst_aa  = (const int*)d_in[4];
    const int* src_at  = (const int*)d_in[5];
    const int* dst_at  = (const int*)d_in[6];
    const int* src_ta  = (const int*)d_in[7];
    const int* dst_ta  = (const int*)d_in[8];
    const float* W1_aa = (const float*)d_in[9];
    const float* b1_aa = (const float*)d_in[10];
    const float* W1_at = (const float*)d_in[11];
    const float* b1_at = (const float*)d_in[12];
    const float* W1_ta = (const float*)d_in[13];
    const float* b1_ta = (const float*)d_in[14];
    const float* W2_aa = (const float*)d_in[15];
    const float* b2_aa = (const float*)d_in[16];
    const float* W2_at = (const float*)d_in[17];
    const float* b2_at = (const float*)d_in[18];
    const float* W2_ta = (const float*)d_in[19];
    const float* b2_ta = (const float*)d_in[20];
    const float* Wp_a  = (const float*)d_in[21];
    const float* bp_a  = (const float*)d_in[22];
    const float* Wp_t  = (const float*)d_in[23];
    const float* bp_t  = (const float*)d_in[24];

    int*   wi  = (int*)d_ws;
    float* wf  = (float*)d_ws;
    unsigned short* csr = (unsigned short*)(wi + O_CSR);
    float* out = (float*)d_out;

    // single memset: 8-copy src-degree histograms + adjacent bucket totals
    hipMemsetAsync(wi + O_SRCH, 0, (size_t)(8 * SRCH_STRIDE + 512) * 4, stream);

    // fused pass 1: single edge read -> LDS bucket sort -> slab flush (+ src degrees)
    p1_fused_kernel<<<NBLK1, 1024, 0, stream>>>(src_aa, dst_aa, src_ta, dst_ta,
                                                src_at, dst_at, wi);

    // fused pass 2 + aux: p2 (self-computed bases) | src coefs | U fuse
    p2_aux_kernel<<<NB + 75, 1024, 0, stream>>>(wi, wf, W2_aa, W2_ta, W2_at,
                                                b2_aa, b2_ta, b2_at,
                                                Wp_a, bp_a, Wp_t, bp_t);

    // conv1: 512 x 1024-thread blocks = 2/CU = full wave occupancy
    conv1_all_kernel<<<C1_AB + C1_TB, 1024, 0, stream>>>(
        x_a, x_t, wi + O_RO, csr,
        wf + O_CAA, wf + O_CTAD, wf + O_CTAS, wf + O_CATS, wf + O_CATD,
        W1_aa, b1_aa, W1_ta, b1_ta, W1_at, b1_at, wf + O_U,
        wf + O_P, wf + O_Q, wf + O_R);

    // conv2 + projection, wave per node
    out_all_kernel<<<(NA + NT) / 4, 256, 0, stream>>>(
        wf + O_P, wf + O_Q, wf + O_R, wi + O_RO, csr,
        wf + O_CAA, wf + O_CTAD, wf + O_CATD, wf + O_U, out);
}

// Round 4
// 236.137 us; speedup vs baseline: 1.7163x; 1.0433x over previous
//
#include <hip/hip_runtime.h>

#define NA 50000
#define NT 25000
#define EAA 800000
#define EAT 400000
#define ETA 400000
#define NSEG 125000          // NA + NA + NT rows: [aa | ta | at]
#define TOTAL_E 1600000
#define NB 489               // coarse buckets of 256 rows
#define NBLK1 391            // pass-1 blocks
#define CHUNK 4096           // edges per pass-1 block
#define CAP 6144             // REC slab capacity per bucket (max observed bucket ~4800)
#define SRCH_STRIDE 75008    // per-copy src-histogram stride: at[50000] | ta[25000] | pad

// conv1 gather: 512 blocks x 1024 threads persistent
#define C1_AB 390            // agent blocks (16 waves each -> 6240 agent wave-streams)
#define C1_TB 122            // target blocks
#define C1_AS (C1_AB * 16)
#define C1_TS (C1_TB * 16)

// dense-B grid
#define NBB_A 782            // ceil(50000/64)
#define NBB_T 391            // ceil(25000/64)

// ---- workspace layout (4-byte element offsets) ----
#define O_SRCH    0          // int[8*75008]
#define O_BTOT    600064     // int[512]
#define O_RO      600576     // int[125001]
#define O_CAA     725584     // float[50000]
#define O_CTAD    775584     // float[50000]
#define O_CATD    825584     // float[25000]
#define O_CATS    850584     // float[50000]
#define O_CTAS    900584     // float[25000]
#define O_U       925600     // float[512]
#define O_P       926112     // float[100000]
#define O_Q       1026112    // float[100000]
#define O_R       1126112    // float[50000]
#define O_REC     1176112    // int[NB*CAP=3004416]
#define O_CSR     4180528    // ushort[1600000] = 800000 ints
#define O_AGA     4980528    // float[50000*64] = 3.2M  (agent agg: [ci*(aggA+self) | ctd*aggT])
#define O_AGT     8180528    // float[25000*32] = 0.8M  (target agg: catd*aggAT)

__device__ __forceinline__ float bcast(float v, int l) {
    return __int_as_float(__builtin_amdgcn_readlane(__float_as_int(v), l));
}

// ---------- fused pass 1: load edges once -> LDS bucket sort -> slab flush (+ src degrees) ----------
__global__ void __launch_bounds__(1024)
p1_fused_kernel(const int* __restrict__ src_aa, const int* __restrict__ dst_aa,
                const int* __restrict__ src_ta, const int* __restrict__ dst_ta,
                const int* __restrict__ src_at, const int* __restrict__ dst_at,
                int* __restrict__ wi) {
    __shared__ int recs[CHUNK];
    __shared__ unsigned short bkt[CHUNK];
    __shared__ int sorted[CHUNK];
    __shared__ unsigned short sbkt[CHUNK];
    __shared__ int cnt[NB];
    __shared__ int cur[NB];
    __shared__ int gbase[NB];
    int b = blockIdx.x, tid = threadIdx.x;
    int* rec_g = wi + O_REC;

    for (int i = tid; i < NB; i += 1024) cnt[i] = 0;
    __syncthreads();

    int t0 = b * CHUNK;
    int n = min(CHUNK, TOTAL_E - t0);
    int* srch = wi + O_SRCH + (b & 7) * SRCH_STRIDE;
    for (int i = tid; i < n; i += 1024) {
        int t = t0 + i, row, s;
        if (t < EAA) {
            row = dst_aa[t]; s = src_aa[t];
        } else if (t < EAA + ETA) {
            int u = t - EAA;
            row = NA + dst_ta[u]; s = src_ta[u];
            atomicAdd(&srch[50000 + s], 1);
        } else {
            int u = t - EAA - ETA;
            row = 2 * NA + dst_at[u]; s = src_at[u];
            atomicAdd(&srch[s], 1);
        }
        int bk = row >> 8;
        recs[i] = ((row & 255) << 16) | s;
        bkt[i] = (unsigned short)bk;
        atomicAdd(&cnt[bk], 1);
    }
    __syncthreads();

    if (tid < NB) gbase[tid] = cnt[tid];
    __syncthreads();
    for (int off = 1; off < NB; off <<= 1) {
        int x = 0;
        if (tid < NB && tid >= off) x = gbase[tid - off];
        __syncthreads();
        if (tid < NB) gbase[tid] += x;
        __syncthreads();
    }
    if (tid < NB) cur[tid] = gbase[tid] - cnt[tid];
    __syncthreads();

    for (int i = tid; i < n; i += 1024) {
        int bk = bkt[i];
        int pos = atomicAdd(&cur[bk], 1);
        sorted[pos] = recs[i];
        sbkt[pos] = (unsigned short)bk;
    }
    __syncthreads();

    for (int bk = tid; bk < NB; bk += 1024) {
        int len = cnt[bk];
        if (len > 0) {
            int gb = atomicAdd(&wi[O_BTOT + bk], len);
            gbase[bk] = bk * CAP + gb - (cur[bk] - len);
        }
    }
    __syncthreads();

    for (int i = tid; i < n; i += 1024) {
        int bk = sbkt[i];
        rec_g[gbase[bk] + i] = sorted[i];
    }
}

// ---------- fused pass 2 + aux ----------
__global__ void __launch_bounds__(1024)
p2_aux_kernel(int* __restrict__ wi, float* __restrict__ wf,
              const float* __restrict__ W2_aa, const float* __restrict__ W2_ta,
              const float* __restrict__ W2_at, const float* __restrict__ b2_aa,
              const float* __restrict__ b2_ta, const float* __restrict__ b2_at,
              const float* __restrict__ Wp_a, const float* __restrict__ bp_a,
              const float* __restrict__ Wp_t, const float* __restrict__ bp_t) {
    int bb = blockIdx.x, tid = threadIdx.x, lane = tid & 63, wid = tid >> 6;
    if (bb < NB) {
        const int* rec = wi + O_REC;
        unsigned short* csr = (unsigned short*)(wi + O_CSR);
        int* ro = wi + O_RO;
        float* caa = wf + O_CAA;
        float* ctad = wf + O_CTAD;
        float* catd = wf + O_CATD;
        __shared__ int deg[256];
        __shared__ int rb[256];
        __shared__ int wsum[16];
        int k = bb;
        int a = (tid < k) ? wi[O_BTOT + tid] : 0;
#pragma unroll
        for (int m = 32; m; m >>= 1) a += __shfl_xor(a, m, 64);
        if (lane == 0) wsum[wid] = a;
        if (tid < 256) deg[tid] = 0;
        __syncthreads();
        int g0 = 0;
#pragma unroll
        for (int w = 0; w < 16; ++w) g0 += wsum[w];
        int s0 = k * CAP;
        int len = wi[O_BTOT + k];
        for (int j = tid; j < len; j += 1024) atomicAdd(&deg[rec[s0 + j] >> 16], 1);
        __syncthreads();
        int v = 0, x = 0;
        if (tid < 256) {
            v = deg[tid];
            x = v;
#pragma unroll
            for (int off = 1; off < 64; off <<= 1) {
                int y = __shfl_up(x, off, 64);
                if (lane >= off) x += y;
            }
            if (lane == 63) wsum[wid] = x;
        }
        __syncthreads();
        if (tid < 256) {
            int wpre = 0;
            for (int w = 0; w < wid; ++w) wpre += wsum[w];
            int excl = x - v + wpre;
            rb[tid] = g0 + excl;
            int g = k * 256 + tid;
            if (g < NSEG) {
                ro[g] = g0 + excl;
                if (g < NA) caa[g] = rsqrtf((float)v + 1.0f);
                else if (g < 2 * NA) ctad[g - NA] = v > 0 ? rsqrtf((float)v) : 0.0f;
                else catd[g - 2 * NA] = v > 0 ? rsqrtf((float)v) : 0.0f;
            }
            if (k == NB - 1 && tid == 0) ro[NSEG] = TOTAL_E;
        }
        __syncthreads();
        for (int j = tid; j < len; j += 1024) {
            int rc = rec[s0 + j];
            int pos = atomicAdd(&rb[rc >> 16], 1);
            csr[pos] = (unsigned short)(rc & 0xFFFF);
        }
    } else if (bb < NB + 74) {
        int t = (bb - NB) * 1024 + tid;
        if (t < 75000) {
            int d = 0;
#pragma unroll
            for (int c = 0; c < 8; ++c) d += wi[O_SRCH + c * SRCH_STRIDE + t];
            float v = d > 0 ? rsqrtf((float)d) : 0.0f;
            if (t < 50000) wf[O_CATS + t] = v;
            else           wf[O_CTAS + (t - 50000)] = v;
        }
    } else {
        float* U = wf + O_U;
        int t = tid;
        if (t < 128) {
            int k = t >> 1, j = t & 1;
            float a = 0.f;
            for (int f = 0; f < 64; ++f) a = fmaf(W2_aa[k * 64 + f], Wp_a[f * 2 + j], a);
            U[t] = a;
        } else if (t < 256) {
            int u = t - 128; int k = u >> 1, j = u & 1;
            float a = 0.f;
            for (int f = 0; f < 64; ++f) a = fmaf(W2_ta[k * 64 + f], Wp_a[f * 2 + j], a);
            U[128 + u] = a;
        } else if (t < 384) {
            int u = t - 256; int k = u >> 1, j = u & 1;
            float a = 0.f;
            for (int f = 0; f < 64; ++f) a = fmaf(W2_at[k * 64 + f], Wp_t[f * 2 + j], a);
            U[256 + u] = a;
        } else if (t < 386) {
            int j = t - 384;
            float a = bp_a[j];
            for (int f = 0; f < 64; ++f) a = fmaf(b2_aa[f] + b2_ta[f], Wp_a[f * 2 + j], a);
            U[384 + j] = a;
        } else if (t < 388) {
            int j = t - 386;
            float a = bp_t[j];
            for (int f = 0; f < 64; ++f) a = fmaf(b2_at[f], Wp_t[f * 2 + j], a);
            U[386 + j] = a;
        }
    }
}

// ---------- conv1 kernel A: GATHER ONLY -> scaled agg rows to workspace.
//            Persistent 1024-thread blocks, 1-deep pipeline, unroll-2 gather, coef-via-shfl.
//            No LDS, no barriers, no matvec (that moved to dense_b_kernel). ----------
__global__ void __launch_bounds__(1024, 4)
conv1_gather_kernel(const float* __restrict__ x_a, const float* __restrict__ x_t,
                    const int* __restrict__ ro, const unsigned short* __restrict__ csr,
                    const float* __restrict__ c_aa, const float* __restrict__ c_ta_d,
                    const float* __restrict__ c_ta_s, const float* __restrict__ c_at_s,
                    const float* __restrict__ c_at_d,
                    float* __restrict__ agg_a, float* __restrict__ agg_t) {
    int lane = threadIdx.x & 63;
    int wid = threadIdx.x >> 6;      // 0..15
    int e8 = lane >> 3, k4 = lane & 7;

    if (blockIdx.x < C1_AB) {
        // ---------- agents ----------
        int i = blockIdx.x * 16 + wid;
        int b0 = ro[i], e0v = ro[i + 1];
        int b1 = ro[NA + i], e1v = ro[NA + i + 1];
        int na = e0v - b0, nt = e1v - b1;
        int sA = (lane < na) ? (int)csr[b0 + lane] : -1;
        int sT = (lane < nt) ? (int)csr[b1 + lane] : -1;
        float cAv = (sA >= 0) ? c_aa[sA] : 0.f;
        float cTv = (sT >= 0) ? c_ta_s[sT] : 0.f;

        while (true) {
            // (1) issue next node's row offsets + current coefs + self row
            int ni = i + C1_AS;
            bool more = ni < NA;
            int nb0 = 0, ne0 = 0, nb1 = 0, ne1 = 0;
            if (more) {
                nb0 = ro[ni]; ne0 = ro[ni + 1];
                nb1 = ro[NA + ni]; ne1 = ro[NA + ni + 1];
            }
            float ci = c_aa[i], ctd = c_ta_d[i];
            float4 xs = make_float4(0.f, 0.f, 0.f, 0.f);
            if (e8 == 0) xs = *(const float4*)(x_a + (size_t)i * 32 + k4 * 4);

            // (2) gathers
            float4 accA = make_float4(0.f, 0.f, 0.f, 0.f);
            float4 accT = make_float4(0.f, 0.f, 0.f, 0.f);
            int nGA = (min(na, 64) + 7) >> 3;
            int nGT = (min(nt, 64) + 7) >> 3;
            int ga = 0;
            for (; ga + 2 <= nGA; ga += 2) {
                int s0 = __shfl(sA, ga * 8 + e8, 64);
                int s1 = __shfl(sA, ga * 8 + 8 + e8, 64);
                float w0 = __shfl(cAv, ga * 8 + e8, 64);
                float w1 = __shfl(cAv, ga * 8 + 8 + e8, 64);
                float4 x0 = make_float4(0.f, 0.f, 0.f, 0.f), x1 = x0;
                if (s0 >= 0) x0 = *(const float4*)(x_a + (size_t)s0 * 32 + k4 * 4);
                if (s1 >= 0) x1 = *(const float4*)(x_a + (size_t)s1 * 32 + k4 * 4);
                accA.x = fmaf(x0.x, w0, accA.x); accA.y = fmaf(x0.y, w0, accA.y);
                accA.z = fmaf(x0.z, w0, accA.z); accA.w = fmaf(x0.w, w0, accA.w);
                accA.x = fmaf(x1.x, w1, accA.x); accA.y = fmaf(x1.y, w1, accA.y);
                accA.z = fmaf(x1.z, w1, accA.z); accA.w = fmaf(x1.w, w1, accA.w);
            }
            if (ga < nGA) {
                int s0 = __shfl(sA, ga * 8 + e8, 64);
                float w0 = __shfl(cAv, ga * 8 + e8, 64);
                float4 x0 = make_float4(0.f, 0.f, 0.f, 0.f);
                if (s0 >= 0) x0 = *(const float4*)(x_a + (size_t)s0 * 32 + k4 * 4);
                accA.x = fmaf(x0.x, w0, accA.x); accA.y = fmaf(x0.y, w0, accA.y);
                accA.z = fmaf(x0.z, w0, accA.z); accA.w = fmaf(x0.w, w0, accA.w);
            }
            for (int j = b0 + 64 + e8; j < e0v; j += 8) {
                int s = csr[j];
                float w = c_aa[s];
                float4 xv = *(const float4*)(x_a + (size_t)s * 32 + k4 * 4);
                accA.x = fmaf(xv.x, w, accA.x); accA.y = fmaf(xv.y, w, accA.y);
                accA.z = fmaf(xv.z, w, accA.z); accA.w = fmaf(xv.w, w, accA.w);
            }
            int gt = 0;
            for (; gt + 2 <= nGT; gt += 2) {
                int s0 = __shfl(sT, gt * 8 + e8, 64);
                int s1 = __shfl(sT, gt * 8 + 8 + e8, 64);
                float w0 = __shfl(cTv, gt * 8 + e8, 64);
                float w1 = __shfl(cTv, gt * 8 + 8 + e8, 64);
                float4 x0 = make_float4(0.f, 0.f, 0.f, 0.f), x1 = x0;
                if (s0 >= 0) x0 = *(const float4*)(x_t + (size_t)s0 * 32 + k4 * 4);
                if (s1 >= 0) x1 = *(const float4*)(x_t + (size_t)s1 * 32 + k4 * 4);
                accT.x = fmaf(x0.x, w0, accT.x); accT.y = fmaf(x0.y, w0, accT.y);
                accT.z = fmaf(x0.z, w0, accT.z); accT.w = fmaf(x0.w, w0, accT.w);
                accT.x = fmaf(x1.x, w1, accT.x); accT.y = fmaf(x1.y, w1, accT.y);
                accT.z = fmaf(x1.z, w1, accT.z); accT.w = fmaf(x1.w, w1, accT.w);
            }
            if (gt < nGT) {
                int s0 = __shfl(sT, gt * 8 + e8, 64);
                float w0 = __shfl(cTv, gt * 8 + e8, 64);
                float4 x0 = make_float4(0.f, 0.f, 0.f, 0.f);
                if (s0 >= 0) x0 = *(const float4*)(x_t + (size_t)s0 * 32 + k4 * 4);
                accT.x = fmaf(x0.x, w0, accT.x); accT.y = fmaf(x0.y, w0, accT.y);
                accT.z = fmaf(x0.z, w0, accT.z); accT.w = fmaf(x0.w, w0, accT.w);
            }
            for (int j = b1 + 64 + e8; j < e1v; j += 8) {
                int s = csr[j];
                float w = c_ta_s[s];
                float4 xv = *(const float4*)(x_t + (size_t)s * 32 + k4 * 4);
                accT.x = fmaf(xv.x, w, accT.x); accT.y = fmaf(xv.y, w, accT.y);
                accT.z = fmaf(xv.z, w, accT.z); accT.w = fmaf(xv.w, w, accT.w);
            }
            // self-loop
            accA.x = fmaf(xs.x, ci, accA.x); accA.y = fmaf(xs.y, ci, accA.y);
            accA.z = fmaf(xs.z, ci, accA.z); accA.w = fmaf(xs.w, ci, accA.w);

            // (3) issue next node's csr preload
            int nsA = -1, nsT = -1;
            if (more) {
                int nna = ne0 - nb0, nnt = ne1 - nb1;
                nsA = (lane < nna) ? (int)csr[nb0 + lane] : -1;
                nsT = (lane < nnt) ? (int)csr[nb1 + lane] : -1;
            }

            // (4) reduce across e8 groups
#pragma unroll
            for (int m = 8; m <= 32; m <<= 1) {
                accA.x += __shfl_xor(accA.x, m, 64);
                accA.y += __shfl_xor(accA.y, m, 64);
                accA.z += __shfl_xor(accA.z, m, 64);
                accA.w += __shfl_xor(accA.w, m, 64);
                accT.x += __shfl_xor(accT.x, m, 64);
                accT.y += __shfl_xor(accT.y, m, 64);
                accT.z += __shfl_xor(accT.z, m, 64);
                accT.w += __shfl_xor(accT.w, m, 64);
            }

            // (5) issue next node's edge-coef gathers
            float ncA = 0.f, ncT = 0.f;
            if (more) {
                ncA = (nsA >= 0) ? c_aa[nsA] : 0.f;
                ncT = (nsT >= 0) ? c_ta_s[nsT] : 0.f;
            }

            // (6) store scaled agg row: [ci*(aggA+self) | ctd*aggT]
            if (e8 == 0) {
                *(float4*)(agg_a + (size_t)i * 64 + k4 * 4) =
                    make_float4(accA.x * ci, accA.y * ci, accA.z * ci, accA.w * ci);
                *(float4*)(agg_a + (size_t)i * 64 + 32 + k4 * 4) =
                    make_float4(accT.x * ctd, accT.y * ctd, accT.z * ctd, accT.w * ctd);
            }

            if (!more) break;
            i = ni;
            b0 = nb0; e0v = ne0; b1 = nb1; e1v = ne1;
            na = ne0 - nb0; nt = ne1 - nb1;
            sA = nsA; sT = nsT; cAv = ncA; cTv = ncT;
        }
    } else {
        // ---------- targets ----------
        int i = (blockIdx.x - C1_AB) * 16 + wid;
        int b0 = ro[2 * NA + i], e0v = ro[2 * NA + i + 1];
        int na = e0v - b0;
        int sA = (lane < na) ? (int)csr[b0 + lane] : -1;
        float cAv = (sA >= 0) ? c_at_s[sA] : 0.f;

        while (true) {
            int ni = i + C1_TS;
            bool more = ni < NT;
            int nb0 = 0, ne0 = 0;
            if (more) { nb0 = ro[2 * NA + ni]; ne0 = ro[2 * NA + ni + 1]; }
            float cd = c_at_d[i];

            float4 acc = make_float4(0.f, 0.f, 0.f, 0.f);
            int nG = (min(na, 64) + 7) >> 3;
            int ga = 0;
            for (; ga + 2 <= nG; ga += 2) {
                int s0 = __shfl(sA, ga * 8 + e8, 64);
                int s1 = __shfl(sA, ga * 8 + 8 + e8, 64);
                float w0 = __shfl(cAv, ga * 8 + e8, 64);
                float w1 = __shfl(cAv, ga * 8 + 8 + e8, 64);
                float4 x0 = make_float4(0.f, 0.f, 0.f, 0.f), x1 = x0;
                if (s0 >= 0) x0 = *(const float4*)(x_a + (size_t)s0 * 32 + k4 * 4);
                if (s1 >= 0) x1 = *(const float4*)(x_a + (size_t)s1 * 32 + k4 * 4);
                acc.x = fmaf(x0.x, w0, acc.x); acc.y = fmaf(x0.y, w0, acc.y);
                acc.z = fmaf(x0.z, w0, acc.z); acc.w = fmaf(x0.w, w0, acc.w);
                acc.x = fmaf(x1.x, w1, acc.x); acc.y = fmaf(x1.y, w1, acc.y);
                acc.z = fmaf(x1.z, w1, acc.z); acc.w = fmaf(x1.w, w1, acc.w);
            }
            if (ga < nG) {
                int s0 = __shfl(sA, ga * 8 + e8, 64);
                float w0 = __shfl(cAv, ga * 8 + e8, 64);
                float4 x0 = make_float4(0.f, 0.f, 0.f, 0.f);
                if (s0 >= 0) x0 = *(const float4*)(x_a + (size_t)s0 * 32 + k4 * 4);
                acc.x = fmaf(x0.x, w0, acc.x); acc.y = fmaf(x0.y, w0, acc.y);
                acc.z = fmaf(x0.z, w0, acc.z); acc.w = fmaf(x0.w, w0, acc.w);
            }
            for (int j = b0 + 64 + e8; j < e0v; j += 8) {
                int s = csr[j];
                float w = c_at_s[s];
                float4 xv = *(const float4*)(x_a + (size_t)s * 32 + k4 * 4);
                acc.x = fmaf(xv.x, w, acc.x); acc.y = fmaf(xv.y, w, acc.y);
                acc.z = fmaf(xv.z, w, acc.z); acc.w = fmaf(xv.w, w, acc.w);
            }

            int nsA = -1;
            if (more) {
                int nna = ne0 - nb0;
                nsA = (lane < nna) ? (int)csr[nb0 + lane] : -1;
            }

#pragma unroll
            for (int m = 8; m <= 32; m <<= 1) {
                acc.x += __shfl_xor(acc.x, m, 64);
                acc.y += __shfl_xor(acc.y, m, 64);
                acc.z += __shfl_xor(acc.z, m, 64);
                acc.w += __shfl_xor(acc.w, m, 64);
            }

            float ncA = 0.f;
            if (more) ncA = (nsA >= 0) ? c_at_s[nsA] : 0.f;

            if (e8 == 0) {
                *(float4*)(agg_t + (size_t)i * 32 + k4 * 4) =
                    make_float4(acc.x * cd, acc.y * cd, acc.z * cd, acc.w * cd);
            }

            if (!more) break;
            i = ni;
            b0 = nb0; e0v = ne0; na = ne0 - nb0;
            sA = nsA; cAv = ncA;
        }
    }
}

// ---------- kernel B: dense transform + fused projection.
//            64-node tiles, W+agg staged in LDS, 4 lanes/node x 16 h-cols, k-major.
//            agents: h = relu(bias + agg[64] @ [W_aa;W_ta]); p = ci*(h.U0), q = cq*(h.U1)
//            targets: h = relu(b_at + agg[32] @ W_at); r = cr*(h.U2) ----------
__global__ void __launch_bounds__(256)
dense_b_kernel(const float* __restrict__ agg_a, const float* __restrict__ agg_t,
               const float* __restrict__ W_aa, const float* __restrict__ W_ta,
               const float* __restrict__ W_at,
               const float* __restrict__ b_aa, const float* __restrict__ b_ta,
               const float* __restrict__ b_at, const float* __restrict__ U,
               const float* __restrict__ c_aa, const float* __restrict__ c_at_s,
               const float* __restrict__ c_ta_s,
               float* __restrict__ p, float* __restrict__ q, float* __restrict__ r) {
    __shared__ float Wc[64 * 68];    // Wc[k*68+f]
    __shared__ float AG[64 * 68];    // AG[n*68+k]
    __shared__ float BI[64];
    __shared__ float UP0[64], UP1[64], UQ0[64], UQ1[64];
    int t = threadIdx.x;
    int nloc = t >> 2;               // 0..63: node within tile
    int f0 = (t & 3) << 4;           // 0,16,32,48: h-column range

    if (blockIdx.x < NBB_A) {
        // ================= agents =================
        for (int idx = t; idx < 4096; idx += 256) {
            int k = idx >> 6, f = idx & 63;
            Wc[k * 68 + f] = (k < 32) ? W_aa[k * 64 + f] : W_ta[(k - 32) * 64 + f];
        }
        if (t < 64) {
            BI[t] = b_aa[t] + b_ta[t];
            UP0[t] = U[t * 2];       UP1[t] = U[t * 2 + 1];
            UQ0[t] = U[256 + t * 2]; UQ1[t] = U[256 + t * 2 + 1];
        }
        int t0 = blockIdx.x * 64;
        for (int idx = t; idx < 1024; idx += 256) {
            int n = idx >> 4, kq = idx & 15;
            int gi = t0 + n;
            float4 v = make_float4(0.f, 0.f, 0.f, 0.f);
            if (gi < NA) v = *(const float4*)(agg_a + (size_t)gi * 64 + kq * 4);
            *(float4*)&AG[n * 68 + kq * 4] = v;
        }
        __syncthreads();

        float4 h0 = *(const float4*)&BI[f0];
        float4 h1 = *(const float4*)&BI[f0 + 4];
        float4 h2 = *(const float4*)&BI[f0 + 8];
        float4 h3 = *(const float4*)&BI[f0 + 12];
        const float* ag = &AG[nloc * 68];
#pragma unroll 8
        for (int k = 0; k < 64; ++k) {
            float a = ag[k];
            const float* w = &Wc[k * 68 + f0];
            float4 w0 = *(const float4*)(w);
            float4 w1 = *(const float4*)(w + 4);
            float4 w2 = *(const float4*)(w + 8);
            float4 w3 = *(const float4*)(w + 12);
            h0.x = fmaf(a, w0.x, h0.x); h0.y = fmaf(a, w0.y, h0.y);
            h0.z = fmaf(a, w0.z, h0.z); h0.w = fmaf(a, w0.w, h0.w);
            h1.x = fmaf(a, w1.x, h1.x); h1.y = fmaf(a, w1.y, h1.y);
            h1.z = fmaf(a, w1.z, h1.z); h1.w = fmaf(a, w1.w, h1.w);
            h2.x = fmaf(a, w2.x, h2.x); h2.y = fmaf(a, w2.y, h2.y);
            h2.z = fmaf(a, w2.z, h2.z); h2.w = fmaf(a, w2.w, h2.w);
            h3.x = fmaf(a, w3.x, h3.x); h3.y = fmaf(a, w3.y, h3.y);
            h3.z = fmaf(a, w3.z, h3.z); h3.w = fmaf(a, w3.w, h3.w);
        }
        float hv[16];
        hv[0] = fmaxf(h0.x, 0.f); hv[1] = fmaxf(h0.y, 0.f);
        hv[2] = fmaxf(h0.z, 0.f); hv[3] = fmaxf(h0.w, 0.f);
        hv[4] = fmaxf(h1.x, 0.f); hv[5] = fmaxf(h1.y, 0.f);
        hv[6] = fmaxf(h1.z, 0.f); hv[7] = fmaxf(h1.w, 0.f);
        hv[8] = fmaxf(h2.x, 0.f); hv[9] = fmaxf(h2.y, 0.f);
        hv[10] = fmaxf(h2.z, 0.f); hv[11] = fmaxf(h2.w, 0.f);
        hv[12] = fmaxf(h3.x, 0.f); hv[13] = fmaxf(h3.y, 0.f);
        hv[14] = fmaxf(h3.z, 0.f); hv[15] = fmaxf(h3.w, 0.f);
        float p0 = 0.f, p1 = 0.f, q0 = 0.f, q1 = 0.f;
#pragma unroll
        for (int ii = 0; ii < 16; ++ii) {
            int f = f0 + ii;
            p0 = fmaf(hv[ii], UP0[f], p0);
            p1 = fmaf(hv[ii], UP1[f], p1);
            q0 = fmaf(hv[ii], UQ0[f], q0);
            q1 = fmaf(hv[ii], UQ1[f], q1);
        }
        p0 += __shfl_xor(p0, 1, 64); p0 += __shfl_xor(p0, 2, 64);
        p1 += __shfl_xor(p1, 1, 64); p1 += __shfl_xor(p1, 2, 64);
        q0 += __shfl_xor(q0, 1, 64); q0 += __shfl_xor(q0, 2, 64);
        q1 += __shfl_xor(q1, 1, 64); q1 += __shfl_xor(q1, 2, 64);
        int gi = t0 + nloc;
        if ((t & 3) == 0 && gi < NA) {
            float ci = c_aa[gi], cq = c_at_s[gi];
            *(float2*)&p[gi * 2] = make_float2(p0 * ci, p1 * ci);
            *(float2*)&q[gi * 2] = make_float2(q0 * cq, q1 * cq);
        }
    } else {
        // ================= targets =================
        for (int idx = t; idx < 2048; idx += 256) {
            int k = idx >> 6, f = idx & 63;
            Wc[k * 68 + f] = W_at[k * 64 + f];
        }
        if (t < 64) {
            BI[t] = b_at[t];
            UP0[t] = U[128 + t * 2]; UP1[t] = U[128 + t * 2 + 1];
        }
        int t0 = (blockIdx.x - NBB_A) * 64;
        for (int idx = t; idx < 512; idx += 256) {
            int n = idx >> 3, kq = idx & 7;
            int gi = t0 + n;
            float4 v = make_float4(0.f, 0.f, 0.f, 0.f);
            if (gi < NT) v = *(const float4*)(agg_t + (size_t)gi * 32 + kq * 4);
            *(float4*)&AG[n * 68 + kq * 4] = v;
        }
        __syncthreads();

        float4 h0 = *(const float4*)&BI[f0];
        float4 h1 = *(const float4*)&BI[f0 + 4];
        float4 h2 = *(const float4*)&BI[f0 + 8];
        float4 h3 = *(const float4*)&BI[f0 + 12];
        const float* ag = &AG[nloc * 68];
#pragma unroll 8
        for (int k = 0; k < 32; ++k) {
            float a = ag[k];
            const float* w = &Wc[k * 68 + f0];
            float4 w0 = *(const float4*)(w);
            float4 w1 = *(const float4*)(w + 4);
            float4 w2 = *(const float4*)(w + 8);
            float4 w3 = *(const float4*)(w + 12);
            h0.x = fmaf(a, w0.x, h0.x); h0.y = fmaf(a, w0.y, h0.y);
            h0.z = fmaf(a, w0.z, h0.z); h0.w = fmaf(a, w0.w, h0.w);
            h1.x = fmaf(a, w1.x, h1.x); h1.y = fmaf(a, w1.y, h1.y);
            h1.z = fmaf(a, w1.z, h1.z); h1.w = fmaf(a, w1.w, h1.w);
            h2.x = fmaf(a, w2.x, h2.x); h2.y = fmaf(a, w2.y, h2.y);
            h2.z = fmaf(a, w2.z, h2.z); h2.w = fmaf(a, w2.w, h2.w);
            h3.x = fmaf(a, w3.x, h3.x); h3.y = fmaf(a, w3.y, h3.y);
            h3.z = fmaf(a, w3.z, h3.z); h3.w = fmaf(a, w3.w, h3.w);
        }
        float hv[16];
        hv[0] = fmaxf(h0.x, 0.f); hv[1] = fmaxf(h0.y, 0.f);
        hv[2] = fmaxf(h0.z, 0.f); hv[3] = fmaxf(h0.w, 0.f);
        hv[4] = fmaxf(h1.x, 0.f); hv[5] = fmaxf(h1.y, 0.f);
        hv[6] = fmaxf(h1.z, 0.f); hv[7] = fmaxf(h1.w, 0.f);
        hv[8] = fmaxf(h2.x, 0.f); hv[9] = fmaxf(h2.y, 0.f);
        hv[10] = fmaxf(h2.z, 0.f); hv[11] = fmaxf(h2.w, 0.f);
        hv[12] = fmaxf(h3.x, 0.f); hv[13] = fmaxf(h3.y, 0.f);
        hv[14] = fmaxf(h3.z, 0.f); hv[15] = fmaxf(h3.w, 0.f);
        float r0 = 0.f, r1 = 0.f;
#pragma unroll
        for (int ii = 0; ii < 16; ++ii) {
            int f = f0 + ii;
            r0 = fmaf(hv[ii], UP0[f], r0);
            r1 = fmaf(hv[ii], UP1[f], r1);
        }
        r0 += __shfl_xor(r0, 1, 64); r0 += __shfl_xor(r0, 2, 64);
        r1 += __shfl_xor(r1, 1, 64); r1 += __shfl_xor(r1, 2, 64);
        int gi = t0 + nloc;
        if ((t & 3) == 0 && gi < NT) {
            float cr = c_ta_s[gi];
            *(float2*)&r[gi * 2] = make_float2(r0 * cr, r1 * cr);
        }
    }
}

// ---------- conv2+proj: one wave per node, 32 edge slots x 2 comps ----------
__global__ void __launch_bounds__(256)
out_all_kernel(const float* __restrict__ p, const float* __restrict__ q,
               const float* __restrict__ r, const int* __restrict__ ro,
               const unsigned short* __restrict__ csr,
               const float* __restrict__ c_aa, const float* __restrict__ c_ta_d,
               const float* __restrict__ c_at_d, const float* __restrict__ U,
               float* __restrict__ out) {
    int wgid = blockIdx.x * 4 + (threadIdx.x >> 6);
    int lane = threadIdx.x & 63;
    int slot = lane >> 1, j = lane & 1;
    if (wgid < NA) {
        int i = wgid;
        int b0 = ro[i], n0 = ro[i + 1] - b0;
        float accA = (slot == 0) ? p[i * 2 + j] : 0.f;
        for (int e = slot; e < n0; e += 32) accA += p[(int)csr[b0 + e] * 2 + j];
        int b1 = ro[NA + i], n1 = ro[NA + i + 1] - b1;
        float accT = 0.f;
        for (int e = slot; e < n1; e += 32) accT += r[(int)csr[b1 + e] * 2 + j];
#pragma unroll
        for (int m = 2; m <= 32; m <<= 1) {
            accA += __shfl_xor(accA, m, 64);
            accT += __shfl_xor(accT, m, 64);
        }
        if (lane < 2) out[i * 2 + j] = U[384 + j] + accA * c_aa[i] + accT * c_ta_d[i];
    } else {
        int i = wgid - NA;
        int b0 = ro[2 * NA + i], n0 = ro[2 * NA + i + 1] - b0;
        float acc = 0.f;
        for (int e = slot; e < n0; e += 32) acc += q[(int)csr[b0 + e] * 2 + j];
#pragma unroll
        for (int m = 2; m <= 32; m <<= 1) acc += __shfl_xor(acc, m, 64);
        if (lane < 2) out[NA * 2 + i * 2 + j] = U[386 + j] + acc * c_at_d[i];
    }
}

extern "C" void kernel_launch(void* const* d_in, const int* in_sizes, int n_in,
                              void* d_out, int out_size, void* d_ws, size_t ws_size,
                              hipStream_t stream) {
    const float* x_a   = (const float*)d_in[1];
    const float* x_t   = (const float*)d_in[2];
    const int* src_aa  = (const int*)d_in[3];
    const int* dst_aa  = (const int*)d_in[4];
    const int* src_at  = (const int*)d_in[5];
    const int* dst_at  = (const int*)d_in[6];
    const int* src_ta  = (const int*)d_in[7];
    const int* dst_ta  = (const int*)d_in[8];
    const float* W1_aa = (const float*)d_in[9];
    const float* b1_aa = (const float*)d_in[10];
    const float* W1_at = (const float*)d_in[11];
    const float* b1_at = (const float*)d_in[12];
    const float* W1_ta = (const float*)d_in[13];
    const float* b1_ta = (const float*)d_in[14];
    const float* W2_aa = (const float*)d_in[15];
    const float* b2_aa = (const float*)d_in[16];
    const float* W2_at = (const float*)d_in[17];
    const float* b2_at = (const float*)d_in[18];
    const float* W2_ta = (const float*)d_in[19];
    const float* b2_ta = (const float*)d_in[20];
    const float* Wp_a  = (const float*)d_in[21];
    const float* bp_a  = (const float*)d_in[22];
    const float* Wp_t  = (const float*)d_in[23];
    const float* bp_t  = (const float*)d_in[24];

    int*   wi  = (int*)d_ws;
    float* wf  = (float*)d_ws;
    unsigned short* csr = (unsigned short*)(wi + O_CSR);
    float* out = (float*)d_out;

    // single memset: 8-copy src-degree histograms + adjacent bucket totals
    hipMemsetAsync(wi + O_SRCH, 0, (size_t)(8 * SRCH_STRIDE + 512) * 4, stream);

    // fused pass 1
    p1_fused_kernel<<<NBLK1, 1024, 0, stream>>>(src_aa, dst_aa, src_ta, dst_ta,
                                                src_at, dst_at, wi);

    // fused pass 2 + aux
    p2_aux_kernel<<<NB + 75, 1024, 0, stream>>>(wi, wf, W2_aa, W2_ta, W2_at,
                                                b2_aa, b2_ta, b2_at,
                                                Wp_a, bp_a, Wp_t, bp_t);

    // conv1-A: gather -> scaled agg rows
    conv1_gather_kernel<<<C1_AB + C1_TB, 1024, 0, stream>>>(
        x_a, x_t, wi + O_RO, csr,
        wf + O_CAA, wf + O_CTAD, wf + O_CTAS, wf + O_CATS, wf + O_CATD,
        wf + O_AGA, wf + O_AGT);

    // conv1-B: dense transform + fused projections
    dense_b_kernel<<<NBB_A + NBB_T, 256, 0, stream>>>(
        wf + O_AGA, wf + O_AGT,
        W1_aa, W1_ta, W1_at, b1_aa, b1_ta, b1_at, wf + O_U,
        wf + O_CAA, wf + O_CATS, wf + O_CTAS,
        wf + O_P, wf + O_Q, wf + O_R);

    // conv2 + projection, wave per node
    out_all_kernel<<<(NA + NT) / 4, 256, 0, stream>>>(
        wf + O_P, wf + O_Q, wf + O_R, wi + O_RO, csr,
        wf + O_CAA, wf + O_CTAD, wf + O_CATD, wf + O_U, out);
}